// Round 4
// baseline (2388.363 us; speedup 1.0000x reference)
//
#include <hip/hip_runtime.h>

#define B_ 64
#define L_ 2048
#define D_ 128
#define LP 2056   // padded rows per batch (3 left, 5 right incl. alignment)
#define PAD 3     // SAME-pad left for W=8

typedef __attribute__((ext_vector_type(8))) short short8;
typedef __attribute__((ext_vector_type(4))) float f32x4;

static __device__ __forceinline__ float bf2f(unsigned short u) {
  return __uint_as_float(((unsigned int)u) << 16);
}
static __device__ __forceinline__ unsigned short f2bf(float f) {
  unsigned int x = __float_as_uint(f);
  unsigned int r = (x + 0x7fffu + ((x >> 16) & 1u)) >> 16;  // RNE
  return (unsigned short)r;
}

// ---------------------------------------------------------------------------
// K0: gather tok -> bf16 padded [B,LP,128]; zero l1pad's pad rows; gather bias;
//     transpose weights to bf16 [n][k] layouts for MFMA B-fragments.
//     Also WhT[n=192][k=64] for the MFMA scan.
// ---------------------------------------------------------------------------
__global__ __launch_bounds__(256) void k_prep(
    const int* __restrict__ code, const float* __restrict__ E,
    const float* __restrict__ bias_table, const float* __restrict__ Wx,
    const float* __restrict__ c1w, const float* __restrict__ c2w,
    const float* __restrict__ Wh,
    unsigned short* __restrict__ tokpad, unsigned short* __restrict__ l1pad,
    unsigned short* __restrict__ WxT, unsigned short* __restrict__ c1wT,
    unsigned short* __restrict__ c2wT, float* __restrict__ biasg,
    unsigned short* __restrict__ WhT)
{
  int id = blockIdx.x * 256 + threadIdx.x;
  const int N0 = B_ * LP * 16;            // tokpad in uint4 (8 bf16) chunks
  if (id < N0) {
    int b = id / (LP * 16); int rem = id % (LP * 16);
    int row = rem >> 4, c8 = rem & 15;
    uint4 o = {0u,0u,0u,0u};
    if (row >= PAD && row < PAD + L_) {
      int cd = code[b * L_ + (row - PAD)];
      const float4* e = (const float4*)(E + (size_t)cd * D_ + c8 * 8);
      float4 e0 = e[0], e1 = e[1];
      o.x = f2bf(e0.x) | ((unsigned int)f2bf(e0.y) << 16);
      o.y = f2bf(e0.z) | ((unsigned int)f2bf(e0.w) << 16);
      o.z = f2bf(e1.x) | ((unsigned int)f2bf(e1.y) << 16);
      o.w = f2bf(e1.z) | ((unsigned int)f2bf(e1.w) << 16);
    }
    ((uint4*)tokpad)[id] = o;
    return;
  }
  id -= N0;
  const int N1 = B_ * 8 * 8;              // l1pad pad rows (8 rows x 8 chunks)
  if (id < N1) {
    int b = id >> 6; int rem = id & 63; int ri = rem >> 3, c8 = rem & 7;
    int row = ri < 3 ? ri : (L_ + ri);    // 0,1,2, 2051..2055
    uint4 z = {0u,0u,0u,0u};
    ((uint4*)l1pad)[(b * LP + row) * 8 + c8] = z;
    return;
  }
  id -= N1;
  const int N2 = B_ * L_;
  if (id < N2) { biasg[id] = bias_table[code[id]]; return; }
  id -= N2;
  const int N3 = 192 * 128;               // WxT[c][d]
  if (id < N3) { int c = id >> 7, d = id & 127; WxT[id] = f2bf(Wx[d * 192 + c]); return; }
  id -= N3;
  const int N4 = 8 * 64 * 128;            // c1wT[w][c][d]
  if (id < N4) {
    int w = id >> 13, c = (id >> 7) & 63, d = id & 127;
    c1wT[id] = f2bf(c1w[(w * 128 + d) * 64 + c]); return;
  }
  id -= N4;
  const int N5 = 8 * 64 * 64;             // c2wT[w][c][d]
  if (id < N5) {
    int w = id >> 12, c = (id >> 6) & 63, d = id & 63;
    c2wT[id] = f2bf(c2w[(w * 64 + d) * 64 + c]); return;
  }
  id -= N5;
  const int N6 = 192 * 64;                // WhT[n][k] = Wh[k][n]
  if (id < N6) {
    int n = id >> 6, k = id & 63;
    WhT[id] = f2bf(Wh[k * 192 + n]);
  }
}

// ---------------------------------------------------------------------------
// K1: x_proj = tok @ Wx + b_gru[0]  -> bf16 [B,L,192]   (MFMA 16x16x32 bf16)
// ---------------------------------------------------------------------------
__global__ __launch_bounds__(256) void k_xproj(
    const unsigned short* __restrict__ tokpad, const unsigned short* __restrict__ WxT,
    const float* __restrict__ bg, unsigned short* __restrict__ xproj)
{
  __shared__ __align__(16) unsigned short At[128 * 136];
  __shared__ __align__(16) unsigned short Bt[192 * 136];
  int b = blockIdx.x >> 4;
  int l0 = (blockIdx.x & 15) << 7;
  int tid = threadIdx.x;
  for (int i = tid; i < 128 * 16; i += 256) {
    int row = i >> 4, c8 = i & 15;
    uint4 v = ((const uint4*)tokpad)[(b * LP + PAD + l0 + row) * 16 + c8];
    *((uint4*)&At[row * 136 + c8 * 8]) = v;
  }
  for (int i = tid; i < 192 * 16; i += 256) {
    int row = i >> 4, c8 = i & 15;
    uint4 v = ((const uint4*)WxT)[i];
    *((uint4*)&Bt[row * 136 + c8 * 8]) = v;
  }
  __syncthreads();
  int wave = tid >> 6, lane = tid & 63;
  int m = lane & 15, q = lane >> 4;
  f32x4 acc[2][12];
  #pragma unroll
  for (int mt = 0; mt < 2; ++mt)
    #pragma unroll
    for (int nt = 0; nt < 12; ++nt) acc[mt][nt] = (f32x4){0.f,0.f,0.f,0.f};
  #pragma unroll
  for (int ks = 0; ks < 4; ++ks) {
    int kof = ks * 32 + q * 8;
    short8 a[2], bb[12];
    #pragma unroll
    for (int mt = 0; mt < 2; ++mt)
      a[mt] = *(const short8*)&At[(wave * 32 + mt * 16 + m) * 136 + kof];
    #pragma unroll
    for (int nt = 0; nt < 12; ++nt)
      bb[nt] = *(const short8*)&Bt[(nt * 16 + m) * 136 + kof];
    #pragma unroll
    for (int mt = 0; mt < 2; ++mt)
      #pragma unroll
      for (int nt = 0; nt < 12; ++nt)
        acc[mt][nt] = __builtin_amdgcn_mfma_f32_16x16x32_bf16(a[mt], bb[nt], acc[mt][nt], 0, 0, 0);
  }
  #pragma unroll
  for (int mt = 0; mt < 2; ++mt) {
    int lrow = l0 + wave * 32 + mt * 16 + q * 4;
    #pragma unroll
    for (int nt = 0; nt < 12; ++nt) {
      int c = nt * 16 + m;                 // C col = lane&15
      float b0 = bg[c];
      #pragma unroll
      for (int r = 0; r < 4; ++r)
        xproj[(size_t)(b * L_ + lrow + r) * 192 + c] = f2bf(acc[mt][nt][r] + b0);
    }
  }
}

// ---------------------------------------------------------------------------
// K2: conv1 = relu(conv8(tok,c1w)+c1b) -> bf16 l1pad rows [3,2051)
// ---------------------------------------------------------------------------
__global__ __launch_bounds__(256) void k_conv1(
    const unsigned short* __restrict__ tokpad, const unsigned short* __restrict__ c1wT,
    const float* __restrict__ c1b, unsigned short* __restrict__ l1pad)
{
  __shared__ __align__(16) unsigned short At[135 * 136];
  __shared__ __align__(16) unsigned short Bw[64 * 136];
  int b = blockIdx.x >> 4;
  int l0 = (blockIdx.x & 15) << 7;
  int tid = threadIdx.x;
  for (int i = tid; i < 135 * 16; i += 256) {
    int row = i >> 4, c8 = i & 15;
    uint4 v = ((const uint4*)tokpad)[(b * LP + l0 + row) * 16 + c8];
    *((uint4*)&At[row * 136 + c8 * 8]) = v;
  }
  int wave = tid >> 6, lane = tid & 63;
  int m = lane & 15, q = lane >> 4;
  f32x4 acc[2][4];
  #pragma unroll
  for (int mt = 0; mt < 2; ++mt)
    #pragma unroll
    for (int nt = 0; nt < 4; ++nt) acc[mt][nt] = (f32x4){0.f,0.f,0.f,0.f};
  for (int w = 0; w < 8; ++w) {
    __syncthreads();                       // covers At (w=0) and Bw reuse
    for (int i = tid; i < 64 * 16; i += 256) {
      int row = i >> 4, c8 = i & 15;
      uint4 v = ((const uint4*)c1wT)[(w * 64 + row) * 16 + c8];
      *((uint4*)&Bw[row * 136 + c8 * 8]) = v;
    }
    __syncthreads();
    #pragma unroll
    for (int ks = 0; ks < 4; ++ks) {
      int kof = ks * 32 + q * 8;
      short8 a[2], bb[4];
      #pragma unroll
      for (int mt = 0; mt < 2; ++mt)
        a[mt] = *(const short8*)&At[(wave * 32 + mt * 16 + m + w) * 136 + kof];
      #pragma unroll
      for (int nt = 0; nt < 4; ++nt)
        bb[nt] = *(const short8*)&Bw[(nt * 16 + m) * 136 + kof];
      #pragma unroll
      for (int mt = 0; mt < 2; ++mt)
        #pragma unroll
        for (int nt = 0; nt < 4; ++nt)
          acc[mt][nt] = __builtin_amdgcn_mfma_f32_16x16x32_bf16(a[mt], bb[nt], acc[mt][nt], 0, 0, 0);
    }
  }
  #pragma unroll
  for (int mt = 0; mt < 2; ++mt) {
    int lrow = l0 + wave * 32 + mt * 16 + q * 4;
    #pragma unroll
    for (int nt = 0; nt < 4; ++nt) {
      int c = nt * 16 + m;
      float bias = c1b[c];
      #pragma unroll
      for (int r = 0; r < 4; ++r) {
        float v = fmaxf(acc[mt][nt][r] + bias, 0.f);
        l1pad[(size_t)(b * LP + PAD + lrow + r) * 64 + c] = f2bf(v);
      }
    }
  }
}

// ---------------------------------------------------------------------------
// K3: conv2 (+c2b, pre h_t multiply) -> bf16 c2out [B,L,64]
// ---------------------------------------------------------------------------
__global__ __launch_bounds__(256) void k_conv2(
    const unsigned short* __restrict__ l1pad, const unsigned short* __restrict__ c2wT,
    const float* __restrict__ c2b, unsigned short* __restrict__ c2o)
{
  __shared__ __align__(16) unsigned short At[135 * 72];
  __shared__ __align__(16) unsigned short Bw[64 * 72];
  int b = blockIdx.x >> 4;
  int l0 = (blockIdx.x & 15) << 7;
  int tid = threadIdx.x;
  for (int i = tid; i < 135 * 8; i += 256) {
    int row = i >> 3, c8 = i & 7;
    uint4 v = ((const uint4*)l1pad)[(b * LP + l0 + row) * 8 + c8];
    *((uint4*)&At[row * 72 + c8 * 8]) = v;
  }
  int wave = tid >> 6, lane = tid & 63;
  int m = lane & 15, q = lane >> 4;
  f32x4 acc[2][4];
  #pragma unroll
  for (int mt = 0; mt < 2; ++mt)
    #pragma unroll
    for (int nt = 0; nt < 4; ++nt) acc[mt][nt] = (f32x4){0.f,0.f,0.f,0.f};
  for (int w = 0; w < 8; ++w) {
    __syncthreads();
    for (int i = tid; i < 64 * 8; i += 256) {
      int row = i >> 3, c8 = i & 7;
      uint4 v = ((const uint4*)c2wT)[(w * 64 + row) * 8 + c8];
      *((uint4*)&Bw[row * 72 + c8 * 8]) = v;
    }
    __syncthreads();
    #pragma unroll
    for (int ks = 0; ks < 2; ++ks) {
      int kof = ks * 32 + q * 8;
      short8 a[2], bb[4];
      #pragma unroll
      for (int mt = 0; mt < 2; ++mt)
        a[mt] = *(const short8*)&At[(wave * 32 + mt * 16 + m + w) * 72 + kof];
      #pragma unroll
      for (int nt = 0; nt < 4; ++nt)
        bb[nt] = *(const short8*)&Bw[(nt * 16 + m) * 72 + kof];
      #pragma unroll
      for (int mt = 0; mt < 2; ++mt)
        #pragma unroll
        for (int nt = 0; nt < 4; ++nt)
          acc[mt][nt] = __builtin_amdgcn_mfma_f32_16x16x32_bf16(a[mt], bb[nt], acc[mt][nt], 0, 0, 0);
    }
  }
  #pragma unroll
  for (int mt = 0; mt < 2; ++mt) {
    int lrow = l0 + wave * 32 + mt * 16 + q * 4;
    #pragma unroll
    for (int nt = 0; nt < 4; ++nt) {
      int c = nt * 16 + m;
      float bias = c2b[c];
      #pragma unroll
      for (int r = 0; r < 4; ++r)
        c2o[(size_t)(b * L_ + lrow + r) * 64 + c] = f2bf(acc[mt][nt][r] + bias);
    }
  }
}

// ---------------------------------------------------------------------------
// K4 v4: MFMA GRU scan. 4 WGs x 16 batches. Per step: [16x64]@[64x192] via
// 12 16x16x32 MFMA tiles; wave w owns N-tiles {w,4+w,8+w} = z/r/hh cols
// 16w..16w+15 -> gate math needs no cross-wave exchange. h double-buffered
// in LDS (bf16, A-frag layout, +8-short row pad = conflict-free), 1 barrier
// per step. Wh in LDS (B-frags re-read: robust vs load-sinking pathology
// that kept R1/R2 weights out of registers). h_old in C-frag registers.
// ---------------------------------------------------------------------------
__global__ __launch_bounds__(256, 1) void k_scan(
    const unsigned short* __restrict__ xproj, const unsigned short* __restrict__ WhT,
    const float* __restrict__ bg, float* __restrict__ h_t)
{
  __shared__ __align__(16) unsigned short Bs[192 * 72];
  __shared__ __align__(16) unsigned short hbuf[2][16 * 72];
  int tid = threadIdx.x;
  int w = tid >> 6, lane = tid & 63;
  int m = lane & 15, q = lane >> 4;
  int b0 = blockIdx.x * 16;

  // stage WhT[192][64] -> LDS [192][72]
  for (int i = tid; i < 192 * 8; i += 256) {
    int row = i >> 3, c8 = i & 7;
    uint4 v = ((const uint4*)WhT)[row * 8 + c8];
    *((uint4*)&Bs[row * 72 + c8 * 8]) = v;
  }
  // zero h buffer 0  (16*72 shorts = 144 uint4)
  for (int i = tid; i < 144; i += 256) {
    uint4 z = {0u,0u,0u,0u};
    ((uint4*)&hbuf[0][0])[i] = z;
  }
  int nz = w * 16 + m;                     // this lane's gate column 0..63
  float bz = bg[192 + nz], br = bg[256 + nz], bh = bg[320 + nz];

  const size_t bstride = (size_t)L_ * 192;
  const unsigned short* xp0 = xproj + (size_t)(b0 + q * 4 + 0) * bstride + nz;
  const unsigned short* xp1 = xproj + (size_t)(b0 + q * 4 + 1) * bstride + nz;
  const unsigned short* xp2 = xproj + (size_t)(b0 + q * 4 + 2) * bstride + nz;
  const unsigned short* xp3 = xproj + (size_t)(b0 + q * 4 + 3) * bstride + nz;

  // prefetch step 0
  unsigned short cxz0 = xp0[0], cxr0 = xp0[64], cxh0 = xp0[128];
  unsigned short cxz1 = xp1[0], cxr1 = xp1[64], cxh1 = xp1[128];
  unsigned short cxz2 = xp2[0], cxr2 = xp2[64], cxh2 = xp2[128];
  unsigned short cxz3 = xp3[0], cxr3 = xp3[64], cxh3 = xp3[128];

  f32x4 h_old = (f32x4){0.f, 0.f, 0.f, 0.f};
  __syncthreads();

  for (int t = 0; t < L_; ++t) {
    // prefetch t+1 (clamped)
    size_t off = (size_t)((t + 1 < L_) ? t + 1 : t) * 192;
    unsigned short nxz0 = xp0[off], nxr0 = xp0[off + 64], nxh0 = xp0[off + 128];
    unsigned short nxz1 = xp1[off], nxr1 = xp1[off + 64], nxh1 = xp1[off + 128];
    unsigned short nxz2 = xp2[off], nxr2 = xp2[off + 64], nxh2 = xp2[off + 128];
    unsigned short nxz3 = xp3[off], nxr3 = xp3[off + 64], nxh3 = xp3[off + 128];

    const unsigned short* hb = &hbuf[t & 1][0];
    short8 a0 = *(const short8*)&hb[m * 72 + q * 8];
    short8 a1 = *(const short8*)&hb[m * 72 + 32 + q * 8];
    short8 b00 = *(const short8*)&Bs[(w * 16 + m) * 72 + q * 8];
    short8 b01 = *(const short8*)&Bs[(w * 16 + m) * 72 + 32 + q * 8];
    short8 b10 = *(const short8*)&Bs[((4 + w) * 16 + m) * 72 + q * 8];
    short8 b11 = *(const short8*)&Bs[((4 + w) * 16 + m) * 72 + 32 + q * 8];
    short8 b20 = *(const short8*)&Bs[((8 + w) * 16 + m) * 72 + q * 8];
    short8 b21 = *(const short8*)&Bs[((8 + w) * 16 + m) * 72 + 32 + q * 8];

    f32x4 Cz = (f32x4){0.f,0.f,0.f,0.f};
    f32x4 Cr = (f32x4){0.f,0.f,0.f,0.f};
    f32x4 Ch = (f32x4){0.f,0.f,0.f,0.f};
    Cz = __builtin_amdgcn_mfma_f32_16x16x32_bf16(a0, b00, Cz, 0, 0, 0);
    Cr = __builtin_amdgcn_mfma_f32_16x16x32_bf16(a0, b10, Cr, 0, 0, 0);
    Ch = __builtin_amdgcn_mfma_f32_16x16x32_bf16(a0, b20, Ch, 0, 0, 0);
    Cz = __builtin_amdgcn_mfma_f32_16x16x32_bf16(a1, b01, Cz, 0, 0, 0);
    Cr = __builtin_amdgcn_mfma_f32_16x16x32_bf16(a1, b11, Cr, 0, 0, 0);
    Ch = __builtin_amdgcn_mfma_f32_16x16x32_bf16(a1, b21, Ch, 0, 0, 0);

    unsigned short* hw = &hbuf[(t + 1) & 1][0];
#define GATE(r, XZ, XR, XH) { \
      float zp = Cz[r] + bz + bf2f(XZ); \
      float zg = 1.f / (1.f + __expf(-zp)); \
      float rp = Cr[r] + br + bf2f(XR); \
      float rg = 1.f / (1.f + __expf(-rp)); \
      float hp = bf2f(XH) + rg * (Ch[r] + bh); \
      float e2 = __expf(-2.f * hp); \
      float hh = (1.f - e2) / (1.f + e2); \
      h_old[r] = zg * h_old[r] + (1.f - zg) * hh; \
      hw[(q * 4 + r) * 72 + nz] = f2bf(h_old[r]); }
    GATE(0, cxz0, cxr0, cxh0)
    GATE(1, cxz1, cxr1, cxh1)
    GATE(2, cxz2, cxr2, cxh2)
    GATE(3, cxz3, cxr3, cxh3)
#undef GATE
    cxz0 = nxz0; cxr0 = nxr0; cxh0 = nxh0;
    cxz1 = nxz1; cxr1 = nxr1; cxh1 = nxh1;
    cxz2 = nxz2; cxr2 = nxr2; cxh2 = nxh2;
    cxz3 = nxz3; cxr3 = nxr3; cxh3 = nxh3;
    __syncthreads();   // writes of t visible before reads of t+1
  }
  h_t[(b0 + q * 4 + 0) * 64 + nz] = h_old[0];
  h_t[(b0 + q * 4 + 1) * 64 + nz] = h_old[1];
  h_t[(b0 + q * 4 + 2) * 64 + nz] = h_old[2];
  h_t[(b0 + q * 4 + 3) * 64 + nz] = h_old[3];
}

// ---------------------------------------------------------------------------
// K5: per-batch tail: L2=c2o*h_t -> l2norm -> conv3 -> softmax alpha ->
//     n_hat = sum alpha*tok -> logits = tok.n_hat + bias -> softmax -> out
// ---------------------------------------------------------------------------
__global__ __launch_bounds__(256) void k_final(
    const unsigned short* __restrict__ tokpad, const unsigned short* __restrict__ c2o,
    const float* __restrict__ h_t, const float* __restrict__ c3w,
    const float* __restrict__ c3b, const float* __restrict__ biasg,
    float* __restrict__ out)
{
  __shared__ float Lf[71 * 65];
  __shared__ float a_lds[2048];
  __shared__ float l_lds[2048];
  __shared__ float red[256];
  __shared__ float nred[512];
  __shared__ float nhat[128];
  __shared__ float ht[64];
  __shared__ float c3[512];
  int b = blockIdx.x, tid = threadIdx.x, lane = tid & 63, wave = tid >> 6;
  if (tid < 64) ht[tid] = h_t[b * 64 + tid];
  for (int i = tid; i < 512; i += 256) c3[i] = c3w[i];
  float c3bias = c3b[0];
  __syncthreads();
  // ---- pass 1: a_logits via normalized features + conv3 (tiles of 64 l) ----
  for (int tile = 0; tile < 32; ++tile) {
    int lt = tile << 6;
    for (int i0 = wave; i0 < 71; i0 += 4) {
      int l = lt - 3 + i0;
      float v = 0.f;
      if (l >= 0 && l < L_) v = bf2f(c2o[((size_t)b * L_ + l) * 64 + lane]) * ht[lane];
      float ss = v * v;
      #pragma unroll
      for (int msk = 1; msk < 64; msk <<= 1) ss += __shfl_xor(ss, msk);
      Lf[i0 * 65 + lane] = v * rsqrtf(ss + 1e-12f);
    }
    __syncthreads();
    {
      int u = lane, part = wave;
      float p = 0.f;
      #pragma unroll
      for (int w = 0; w < 8; ++w)
        #pragma unroll
        for (int cc = 0; cc < 16; ++cc) {
          int c = part * 16 + cc;
          p += Lf[(u + w) * 65 + c] * c3[w * 64 + c];
        }
      red[tid] = p;
    }
    __syncthreads();
    if (tid < 64) a_lds[lt + tid] = red[tid] + red[64 + tid] + red[128 + tid] + red[192 + tid] + c3bias;
    __syncthreads();
  }
  // ---- pass 2: softmax alpha over 2048 ----
  {
    float mx = -1e30f;
    for (int i = tid; i < 2048; i += 256) mx = fmaxf(mx, a_lds[i]);
    #pragma unroll
    for (int msk = 1; msk < 64; msk <<= 1) mx = fmaxf(mx, __shfl_xor(mx, msk));
    if (lane == 0) red[wave] = mx;
    __syncthreads();
    mx = fmaxf(fmaxf(red[0], red[1]), fmaxf(red[2], red[3]));
    float sm = 0.f;
    for (int i = tid; i < 2048; i += 256) sm += __expf(a_lds[i] - mx);
    #pragma unroll
    for (int msk = 1; msk < 64; msk <<= 1) sm += __shfl_xor(sm, msk);
    __syncthreads();
    if (lane == 0) red[wave] = sm;
    __syncthreads();
    sm = red[0] + red[1] + red[2] + red[3];
    float inv = 1.f / sm;
    for (int i = tid; i < 2048; i += 256) a_lds[i] = __expf(a_lds[i] - mx) * inv;
    __syncthreads();
  }
  // ---- pass 3: n_hat[128] = sum_l alpha_l * tok[l][:] ----
  {
    int d2 = tid & 63, g = tid >> 6;
    float ax = 0.f, ay = 0.f;
    for (int l = g; l < L_; l += 4) {
      unsigned int uu = *(const unsigned int*)&tokpad[((size_t)b * LP + PAD + l) * 128 + d2 * 2];
      float al = a_lds[l];
      ax += al * bf2f((unsigned short)(uu & 0xffffu));
      ay += al * bf2f((unsigned short)(uu >> 16));
    }
    nred[g * 128 + d2 * 2] = ax;
    nred[g * 128 + d2 * 2 + 1] = ay;
    __syncthreads();
    if (tid < 128) nhat[tid] = nred[tid] + nred[128 + tid] + nred[256 + tid] + nred[384 + tid];
    __syncthreads();
  }
  // ---- pass 4: logits = tok . n_hat + bias ----
  for (int li = 0; li < 8; ++li) {
    int l = li * 256 + tid;
    const uint4* rowp = (const uint4*)&tokpad[((size_t)b * LP + PAD + l) * 128];
    float s = 0.f;
    #pragma unroll
    for (int jj = 0; jj < 16; ++jj) {
      uint4 uu = rowp[jj];
      s += bf2f((unsigned short)(uu.x & 0xffffu)) * nhat[jj*8+0]
         + bf2f((unsigned short)(uu.x >> 16))     * nhat[jj*8+1]
         + bf2f((unsigned short)(uu.y & 0xffffu)) * nhat[jj*8+2]
         + bf2f((unsigned short)(uu.y >> 16))     * nhat[jj*8+3]
         + bf2f((unsigned short)(uu.z & 0xffffu)) * nhat[jj*8+4]
         + bf2f((unsigned short)(uu.z >> 16))     * nhat[jj*8+5]
         + bf2f((unsigned short)(uu.w & 0xffffu)) * nhat[jj*8+6]
         + bf2f((unsigned short)(uu.w >> 16))     * nhat[jj*8+7];
    }
    l_lds[l] = s + biasg[b * L_ + l];
  }
  __syncthreads();
  // ---- pass 5: final softmax -> out ----
  {
    float mx = -1e30f;
    for (int i = tid; i < 2048; i += 256) mx = fmaxf(mx, l_lds[i]);
    #pragma unroll
    for (int msk = 1; msk < 64; msk <<= 1) mx = fmaxf(mx, __shfl_xor(mx, msk));
    __syncthreads();
    if (lane == 0) red[wave] = mx;
    __syncthreads();
    mx = fmaxf(fmaxf(red[0], red[1]), fmaxf(red[2], red[3]));
    float sm = 0.f;
    for (int i = tid; i < 2048; i += 256) sm += __expf(l_lds[i] - mx);
    #pragma unroll
    for (int msk = 1; msk < 64; msk <<= 1) sm += __shfl_xor(sm, msk);
    __syncthreads();
    if (lane == 0) red[wave] = sm;
    __syncthreads();
    sm = red[0] + red[1] + red[2] + red[3];
    float inv = 1.f / sm;
    for (int i = tid; i < 2048; i += 256) out[b * L_ + i] = __expf(l_lds[i] - mx) * inv;
  }
}

// ---------------------------------------------------------------------------
extern "C" void kernel_launch(void* const* d_in, const int* in_sizes, int n_in,
                              void* d_out, int out_size, void* d_ws, size_t ws_size,
                              hipStream_t stream) {
  const int*   code = (const int*)d_in[0];
  const float* E    = (const float*)d_in[1];
  const float* bt   = (const float*)d_in[2];
  const float* Wx   = (const float*)d_in[3];
  const float* Wh   = (const float*)d_in[4];
  const float* bg   = (const float*)d_in[5];
  const float* c1w  = (const float*)d_in[6];
  const float* c1b  = (const float*)d_in[7];
  const float* c2w  = (const float*)d_in[8];
  const float* c2b  = (const float*)d_in[9];
  const float* c3w  = (const float*)d_in[10];
  const float* c3b  = (const float*)d_in[11];
  char* ws = (char*)d_ws;
  unsigned short* tokpad = (unsigned short*)(ws);               // 33,685,504 B
  unsigned short* l1pad  = (unsigned short*)(ws + 33685504);    // 16,842,752 B
  unsigned short* xproj  = (unsigned short*)(ws + 50528256);    // 50,331,648 B
  unsigned short* c2o    = (unsigned short*)(ws + 100859904);   // 16,777,216 B
  unsigned short* WxT    = (unsigned short*)(ws + 117637120);   //     49,152 B
  unsigned short* c1wT   = (unsigned short*)(ws + 117686272);   //    131,072 B
  unsigned short* c2wT   = (unsigned short*)(ws + 117817344);   //     65,536 B
  float*          htp    = (float*)(ws + 117882880);            //     16,384 B
  float*          biasg  = (float*)(ws + 117899264);            //    524,288 B
  unsigned short* WhTg   = (unsigned short*)(ws + 118423552);   //     24,576 B
  // total ws use: 118,448,128 B

  k_prep <<<9280, 256, 0, stream>>>(code, E, bt, Wx, c1w, c2w, Wh,
                                    tokpad, l1pad, WxT, c1wT, c2wT, biasg, WhTg);
  k_xproj<<<1024, 256, 0, stream>>>(tokpad, WxT, bg, xproj);
  k_scan <<<4, 256, 0, stream>>>(xproj, WhTg, bg, htp);
  k_conv1<<<1024, 256, 0, stream>>>(tokpad, c1wT, c1b, l1pad);
  k_conv2<<<1024, 256, 0, stream>>>(l1pad, c2wT, c2b, c2o);
  k_final<<<64, 256, 0, stream>>>(tokpad, c2o, htp, c3w, c3b, biasg, (float*)d_out);
}

// Round 5
// 1747.823 us; speedup vs baseline: 1.3665x; 1.3665x over previous
//
#include <hip/hip_runtime.h>

#define B_ 64
#define L_ 2048
#define D_ 128
#define LP 2056   // padded rows per batch (3 left, 5 right incl. alignment)
#define PAD 3     // SAME-pad left for W=8

typedef __attribute__((ext_vector_type(8))) short short8;
typedef __attribute__((ext_vector_type(4))) float f32x4;

static __device__ __forceinline__ float bf2f(unsigned short u) {
  return __uint_as_float(((unsigned int)u) << 16);
}
static __device__ __forceinline__ unsigned short f2bf(float f) {
  unsigned int x = __float_as_uint(f);
  unsigned int r = (x + 0x7fffu + ((x >> 16) & 1u)) >> 16;  // RNE
  return (unsigned short)r;
}

// ---------------------------------------------------------------------------
// K0: gather tok -> bf16 padded [B,LP,128]; zero l1pad's pad rows; gather bias;
//     transpose weights to bf16 [n][k] layouts for MFMA B-fragments.
// ---------------------------------------------------------------------------
__global__ __launch_bounds__(256) void k_prep(
    const int* __restrict__ code, const float* __restrict__ E,
    const float* __restrict__ bias_table, const float* __restrict__ Wx,
    const float* __restrict__ c1w, const float* __restrict__ c2w,
    unsigned short* __restrict__ tokpad, unsigned short* __restrict__ l1pad,
    unsigned short* __restrict__ WxT, unsigned short* __restrict__ c1wT,
    unsigned short* __restrict__ c2wT, float* __restrict__ biasg)
{
  int id = blockIdx.x * 256 + threadIdx.x;
  const int N0 = B_ * LP * 16;            // tokpad in uint4 (8 bf16) chunks
  if (id < N0) {
    int b = id / (LP * 16); int rem = id % (LP * 16);
    int row = rem >> 4, c8 = rem & 15;
    uint4 o = {0u,0u,0u,0u};
    if (row >= PAD && row < PAD + L_) {
      int cd = code[b * L_ + (row - PAD)];
      const float4* e = (const float4*)(E + (size_t)cd * D_ + c8 * 8);
      float4 e0 = e[0], e1 = e[1];
      o.x = f2bf(e0.x) | ((unsigned int)f2bf(e0.y) << 16);
      o.y = f2bf(e0.z) | ((unsigned int)f2bf(e0.w) << 16);
      o.z = f2bf(e1.x) | ((unsigned int)f2bf(e1.y) << 16);
      o.w = f2bf(e1.z) | ((unsigned int)f2bf(e1.w) << 16);
    }
    ((uint4*)tokpad)[id] = o;
    return;
  }
  id -= N0;
  const int N1 = B_ * 8 * 8;              // l1pad pad rows (8 rows x 8 chunks)
  if (id < N1) {
    int b = id >> 6; int rem = id & 63; int ri = rem >> 3, c8 = rem & 7;
    int row = ri < 3 ? ri : (L_ + ri);    // 0,1,2, 2051..2055
    uint4 z = {0u,0u,0u,0u};
    ((uint4*)l1pad)[(b * LP + row) * 8 + c8] = z;
    return;
  }
  id -= N1;
  const int N2 = B_ * L_;
  if (id < N2) { biasg[id] = bias_table[code[id]]; return; }
  id -= N2;
  const int N3 = 192 * 128;               // WxT[c][d]
  if (id < N3) { int c = id >> 7, d = id & 127; WxT[id] = f2bf(Wx[d * 192 + c]); return; }
  id -= N3;
  const int N4 = 8 * 64 * 128;            // c1wT[w][c][d]
  if (id < N4) {
    int w = id >> 13, c = (id >> 7) & 63, d = id & 127;
    c1wT[id] = f2bf(c1w[(w * 128 + d) * 64 + c]); return;
  }
  id -= N4;
  const int N5 = 8 * 64 * 64;             // c2wT[w][c][d]
  if (id < N5) {
    int w = id >> 12, c = (id >> 6) & 63, d = id & 63;
    c2wT[id] = f2bf(c2w[(w * 64 + d) * 64 + c]);
  }
}

// ---------------------------------------------------------------------------
// K1: x_proj = tok @ Wx + b_gru[0]  -> bf16 [B,L,192]   (MFMA 16x16x32 bf16)
// ---------------------------------------------------------------------------
__global__ __launch_bounds__(256) void k_xproj(
    const unsigned short* __restrict__ tokpad, const unsigned short* __restrict__ WxT,
    const float* __restrict__ bg, unsigned short* __restrict__ xproj)
{
  __shared__ __align__(16) unsigned short At[128 * 136];
  __shared__ __align__(16) unsigned short Bt[192 * 136];
  int b = blockIdx.x >> 4;
  int l0 = (blockIdx.x & 15) << 7;
  int tid = threadIdx.x;
  for (int i = tid; i < 128 * 16; i += 256) {
    int row = i >> 4, c8 = i & 15;
    uint4 v = ((const uint4*)tokpad)[(b * LP + PAD + l0 + row) * 16 + c8];
    *((uint4*)&At[row * 136 + c8 * 8]) = v;
  }
  for (int i = tid; i < 192 * 16; i += 256) {
    int row = i >> 4, c8 = i & 15;
    uint4 v = ((const uint4*)WxT)[i];
    *((uint4*)&Bt[row * 136 + c8 * 8]) = v;
  }
  __syncthreads();
  int wave = tid >> 6, lane = tid & 63;
  int m = lane & 15, q = lane >> 4;
  f32x4 acc[2][12];
  #pragma unroll
  for (int mt = 0; mt < 2; ++mt)
    #pragma unroll
    for (int nt = 0; nt < 12; ++nt) acc[mt][nt] = (f32x4){0.f,0.f,0.f,0.f};
  #pragma unroll
  for (int ks = 0; ks < 4; ++ks) {
    int kof = ks * 32 + q * 8;
    short8 a[2], bb[12];
    #pragma unroll
    for (int mt = 0; mt < 2; ++mt)
      a[mt] = *(const short8*)&At[(wave * 32 + mt * 16 + m) * 136 + kof];
    #pragma unroll
    for (int nt = 0; nt < 12; ++nt)
      bb[nt] = *(const short8*)&Bt[(nt * 16 + m) * 136 + kof];
    #pragma unroll
    for (int mt = 0; mt < 2; ++mt)
      #pragma unroll
      for (int nt = 0; nt < 12; ++nt)
        acc[mt][nt] = __builtin_amdgcn_mfma_f32_16x16x32_bf16(a[mt], bb[nt], acc[mt][nt], 0, 0, 0);
  }
  #pragma unroll
  for (int mt = 0; mt < 2; ++mt) {
    int lrow = l0 + wave * 32 + mt * 16 + q * 4;
    #pragma unroll
    for (int nt = 0; nt < 12; ++nt) {
      int c = nt * 16 + m;                 // C col = lane&15
      float b0 = bg[c];
      #pragma unroll
      for (int r = 0; r < 4; ++r)
        xproj[(size_t)(b * L_ + lrow + r) * 192 + c] = f2bf(acc[mt][nt][r] + b0);
    }
  }
}

// ---------------------------------------------------------------------------
// K2: conv1 = relu(conv8(tok,c1w)+c1b) -> bf16 l1pad rows [3,2051)
// ---------------------------------------------------------------------------
__global__ __launch_bounds__(256) void k_conv1(
    const unsigned short* __restrict__ tokpad, const unsigned short* __restrict__ c1wT,
    const float* __restrict__ c1b, unsigned short* __restrict__ l1pad)
{
  __shared__ __align__(16) unsigned short At[135 * 136];
  __shared__ __align__(16) unsigned short Bw[64 * 136];
  int b = blockIdx.x >> 4;
  int l0 = (blockIdx.x & 15) << 7;
  int tid = threadIdx.x;
  for (int i = tid; i < 135 * 16; i += 256) {
    int row = i >> 4, c8 = i & 15;
    uint4 v = ((const uint4*)tokpad)[(b * LP + l0 + row) * 16 + c8];
    *((uint4*)&At[row * 136 + c8 * 8]) = v;
  }
  int wave = tid >> 6, lane = tid & 63;
  int m = lane & 15, q = lane >> 4;
  f32x4 acc[2][4];
  #pragma unroll
  for (int mt = 0; mt < 2; ++mt)
    #pragma unroll
    for (int nt = 0; nt < 4; ++nt) acc[mt][nt] = (f32x4){0.f,0.f,0.f,0.f};
  for (int w = 0; w < 8; ++w) {
    __syncthreads();                       // covers At (w=0) and Bw reuse
    for (int i = tid; i < 64 * 16; i += 256) {
      int row = i >> 4, c8 = i & 15;
      uint4 v = ((const uint4*)c1wT)[(w * 64 + row) * 16 + c8];
      *((uint4*)&Bw[row * 136 + c8 * 8]) = v;
    }
    __syncthreads();
    #pragma unroll
    for (int ks = 0; ks < 4; ++ks) {
      int kof = ks * 32 + q * 8;
      short8 a[2], bb[4];
      #pragma unroll
      for (int mt = 0; mt < 2; ++mt)
        a[mt] = *(const short8*)&At[(wave * 32 + mt * 16 + m + w) * 136 + kof];
      #pragma unroll
      for (int nt = 0; nt < 4; ++nt)
        bb[nt] = *(const short8*)&Bw[(nt * 16 + m) * 136 + kof];
      #pragma unroll
      for (int mt = 0; mt < 2; ++mt)
        #pragma unroll
        for (int nt = 0; nt < 4; ++nt)
          acc[mt][nt] = __builtin_amdgcn_mfma_f32_16x16x32_bf16(a[mt], bb[nt], acc[mt][nt], 0, 0, 0);
    }
  }
  #pragma unroll
  for (int mt = 0; mt < 2; ++mt) {
    int lrow = l0 + wave * 32 + mt * 16 + q * 4;
    #pragma unroll
    for (int nt = 0; nt < 4; ++nt) {
      int c = nt * 16 + m;
      float bias = c1b[c];
      #pragma unroll
      for (int r = 0; r < 4; ++r) {
        float v = fmaxf(acc[mt][nt][r] + bias, 0.f);
        l1pad[(size_t)(b * LP + PAD + lrow + r) * 64 + c] = f2bf(v);
      }
    }
  }
}

// ---------------------------------------------------------------------------
// K3: conv2 (+c2b, pre h_t multiply) -> bf16 c2out [B,L,64]
// ---------------------------------------------------------------------------
__global__ __launch_bounds__(256) void k_conv2(
    const unsigned short* __restrict__ l1pad, const unsigned short* __restrict__ c2wT,
    const float* __restrict__ c2b, unsigned short* __restrict__ c2o)
{
  __shared__ __align__(16) unsigned short At[135 * 72];
  __shared__ __align__(16) unsigned short Bw[64 * 72];
  int b = blockIdx.x >> 4;
  int l0 = (blockIdx.x & 15) << 7;
  int tid = threadIdx.x;
  for (int i = tid; i < 135 * 8; i += 256) {
    int row = i >> 3, c8 = i & 7;
    uint4 v = ((const uint4*)l1pad)[(b * LP + l0 + row) * 8 + c8];
    *((uint4*)&At[row * 72 + c8 * 8]) = v;
  }
  int wave = tid >> 6, lane = tid & 63;
  int m = lane & 15, q = lane >> 4;
  f32x4 acc[2][4];
  #pragma unroll
  for (int mt = 0; mt < 2; ++mt)
    #pragma unroll
    for (int nt = 0; nt < 4; ++nt) acc[mt][nt] = (f32x4){0.f,0.f,0.f,0.f};
  for (int w = 0; w < 8; ++w) {
    __syncthreads();
    for (int i = tid; i < 64 * 8; i += 256) {
      int row = i >> 3, c8 = i & 7;
      uint4 v = ((const uint4*)c2wT)[(w * 64 + row) * 8 + c8];
      *((uint4*)&Bw[row * 72 + c8 * 8]) = v;
    }
    __syncthreads();
    #pragma unroll
    for (int ks = 0; ks < 2; ++ks) {
      int kof = ks * 32 + q * 8;
      short8 a[2], bb[4];
      #pragma unroll
      for (int mt = 0; mt < 2; ++mt)
        a[mt] = *(const short8*)&At[(wave * 32 + mt * 16 + m + w) * 72 + kof];
      #pragma unroll
      for (int nt = 0; nt < 4; ++nt)
        bb[nt] = *(const short8*)&Bw[(nt * 16 + m) * 72 + kof];
      #pragma unroll
      for (int mt = 0; mt < 2; ++mt)
        #pragma unroll
        for (int nt = 0; nt < 4; ++nt)
          acc[mt][nt] = __builtin_amdgcn_mfma_f32_16x16x32_bf16(a[mt], bb[nt], acc[mt][nt], 0, 0, 0);
    }
  }
  #pragma unroll
  for (int mt = 0; mt < 2; ++mt) {
    int lrow = l0 + wave * 32 + mt * 16 + q * 4;
    #pragma unroll
    for (int nt = 0; nt < 4; ++nt) {
      int c = nt * 16 + m;
      float bias = c2b[c];
      #pragma unroll
      for (int r = 0; r < 4; ++r)
        c2o[(size_t)(b * L_ + lrow + r) * 64 + c] = f2bf(acc[mt][nt][r] + bias);
    }
  }
}

// ---------------------------------------------------------------------------
// K4 v5: GRU scan, back to R2 structure (3 waves/batch, 64 WGs) + the fix:
// weights pass through an empty inline-asm ("+v") once before the loop.
// An asm output cannot be rematerialized from memory, so the 64 weights
// stay VGPR-resident (R1: alloca->scratch, VGPR=44; R2: named float4 still
// re-loaded per step, VGPR=44; R3 MFMA variant: LDS conflicts + no hoist).
// Waves 0/1 apply sigmoid pre-barrier; wave2 does tanh+blend post-barrier.
// ---------------------------------------------------------------------------
__global__ __launch_bounds__(192, 1) void k_scan(
    const unsigned short* __restrict__ xproj, const float* __restrict__ Wh,
    const float* __restrict__ bg, float* __restrict__ h_t)
{
  int b = blockIdx.x;
  int tid = threadIdx.x;
  int wave = tid >> 6, j = tid & 63;
  int o = wave * 64 + j;                  // output column 0..191

#define DECL_W(i) float4 w##i = {Wh[(4*i+0)*192+o], Wh[(4*i+1)*192+o], \
                                 Wh[(4*i+2)*192+o], Wh[(4*i+3)*192+o]};
  DECL_W(0)  DECL_W(1)  DECL_W(2)  DECL_W(3)
  DECL_W(4)  DECL_W(5)  DECL_W(6)  DECL_W(7)
  DECL_W(8)  DECL_W(9)  DECL_W(10) DECL_W(11)
  DECL_W(12) DECL_W(13) DECL_W(14) DECL_W(15)
#undef DECL_W
  // Opacity barrier: forces the 64 weight values to live in VGPRs; the
  // compiler can no longer re-load them from Wh inside the loop.
#define OPAQ(i) asm volatile("" : "+v"(w##i.x), "+v"(w##i.y), "+v"(w##i.z), "+v"(w##i.w));
  OPAQ(0)  OPAQ(1)  OPAQ(2)  OPAQ(3)
  OPAQ(4)  OPAQ(5)  OPAQ(6)  OPAQ(7)
  OPAQ(8)  OPAQ(9)  OPAQ(10) OPAQ(11)
  OPAQ(12) OPAQ(13) OPAQ(14) OPAQ(15)
#undef OPAQ
  float bias = bg[192 + o];               // b_gru[1][o]

  __shared__ __align__(16) float h_lds[64];
  __shared__ float s_z[64];
  __shared__ float s_r[64];
  if (wave == 2) h_lds[j] = 0.f;
  float h_old = 0.f;                      // wave2's private copy of h[j]

  const unsigned short* xp = xproj + (size_t)b * L_ * 192 + o;
  unsigned short x0 = xp[0];
  unsigned short x1 = xp[192];
  const float4* hl4 = (const float4*)h_lds;

  for (int t = 0; t < L_; ++t) {
    __syncthreads();                      // barrier A: h_lds ready, s_* free
    int tn = (t + 2 < L_) ? t + 2 : (L_ - 1);
    unsigned short x2 = xp[(size_t)tn * 192];

    float a0 = bias, a1 = 0.f, a2 = 0.f, a3 = 0.f;
#define ACC_W(i) { float4 h4 = hl4[i]; \
    a0 = fmaf(h4.x, w##i.x, a0); a1 = fmaf(h4.y, w##i.y, a1); \
    a2 = fmaf(h4.z, w##i.z, a2); a3 = fmaf(h4.w, w##i.w, a3); }
    ACC_W(0)  ACC_W(1)  ACC_W(2)  ACC_W(3)
    ACC_W(4)  ACC_W(5)  ACC_W(6)  ACC_W(7)
    ACC_W(8)  ACC_W(9)  ACC_W(10) ACC_W(11)
    ACC_W(12) ACC_W(13) ACC_W(14) ACC_W(15)
#undef ACC_W
    float s = (a0 + a1) + (a2 + a3);      // recurrent preact for column o
    float xv = bf2f(x0);

    if (wave == 0)      s_z[j] = 1.f / (1.f + __expf(-(xv + s)));   // z
    else if (wave == 1) s_r[j] = 1.f / (1.f + __expf(-(xv + s)));   // r
    __syncthreads();                      // barrier B: gates visible, h_lds free
    if (wave == 2) {
      float z = s_z[j], r = s_r[j];
      float e2 = __expf(-2.f * (xv + r * s));
      float hh = fmaf(2.f, __frcp_rn(1.f + e2), -1.f); // tanh
      h_old = z * h_old + (1.f - z) * hh;
      h_lds[j] = h_old;
    }
    x0 = x1; x1 = x2;
  }
  if (wave == 2) h_t[b * 64 + j] = h_old;
}

// ---------------------------------------------------------------------------
// K5: per-batch tail: L2=c2o*h_t -> l2norm -> conv3 -> softmax alpha ->
//     n_hat = sum alpha*tok -> logits = tok.n_hat + bias -> softmax -> out
// ---------------------------------------------------------------------------
__global__ __launch_bounds__(256) void k_final(
    const unsigned short* __restrict__ tokpad, const unsigned short* __restrict__ c2o,
    const float* __restrict__ h_t, const float* __restrict__ c3w,
    const float* __restrict__ c3b, const float* __restrict__ biasg,
    float* __restrict__ out)
{
  __shared__ float Lf[71 * 65];
  __shared__ float a_lds[2048];
  __shared__ float l_lds[2048];
  __shared__ float red[256];
  __shared__ float nred[512];
  __shared__ float nhat[128];
  __shared__ float ht[64];
  __shared__ float c3[512];
  int b = blockIdx.x, tid = threadIdx.x, lane = tid & 63, wave = tid >> 6;
  if (tid < 64) ht[tid] = h_t[b * 64 + tid];
  for (int i = tid; i < 512; i += 256) c3[i] = c3w[i];
  float c3bias = c3b[0];
  __syncthreads();
  // ---- pass 1: a_logits via normalized features + conv3 (tiles of 64 l) ----
  for (int tile = 0; tile < 32; ++tile) {
    int lt = tile << 6;
    for (int i0 = wave; i0 < 71; i0 += 4) {
      int l = lt - 3 + i0;
      float v = 0.f;
      if (l >= 0 && l < L_) v = bf2f(c2o[((size_t)b * L_ + l) * 64 + lane]) * ht[lane];
      float ss = v * v;
      #pragma unroll
      for (int msk = 1; msk < 64; msk <<= 1) ss += __shfl_xor(ss, msk);
      Lf[i0 * 65 + lane] = v * rsqrtf(ss + 1e-12f);
    }
    __syncthreads();
    {
      int u = lane, part = wave;
      float p = 0.f;
      #pragma unroll
      for (int w = 0; w < 8; ++w)
        #pragma unroll
        for (int cc = 0; cc < 16; ++cc) {
          int c = part * 16 + cc;
          p += Lf[(u + w) * 65 + c] * c3[w * 64 + c];
        }
      red[tid] = p;
    }
    __syncthreads();
    if (tid < 64) a_lds[lt + tid] = red[tid] + red[64 + tid] + red[128 + tid] + red[192 + tid] + c3bias;
    __syncthreads();
  }
  // ---- pass 2: softmax alpha over 2048 ----
  {
    float mx = -1e30f;
    for (int i = tid; i < 2048; i += 256) mx = fmaxf(mx, a_lds[i]);
    #pragma unroll
    for (int msk = 1; msk < 64; msk <<= 1) mx = fmaxf(mx, __shfl_xor(mx, msk));
    if (lane == 0) red[wave] = mx;
    __syncthreads();
    mx = fmaxf(fmaxf(red[0], red[1]), fmaxf(red[2], red[3]));
    float sm = 0.f;
    for (int i = tid; i < 2048; i += 256) sm += __expf(a_lds[i] - mx);
    #pragma unroll
    for (int msk = 1; msk < 64; msk <<= 1) sm += __shfl_xor(sm, msk);
    __syncthreads();
    if (lane == 0) red[wave] = sm;
    __syncthreads();
    sm = red[0] + red[1] + red[2] + red[3];
    float inv = 1.f / sm;
    for (int i = tid; i < 2048; i += 256) a_lds[i] = __expf(a_lds[i] - mx) * inv;
    __syncthreads();
  }
  // ---- pass 3: n_hat[128] = sum_l alpha_l * tok[l][:] ----
  {
    int d2 = tid & 63, g = tid >> 6;
    float ax = 0.f, ay = 0.f;
    for (int l = g; l < L_; l += 4) {
      unsigned int uu = *(const unsigned int*)&tokpad[((size_t)b * LP + PAD + l) * 128 + d2 * 2];
      float al = a_lds[l];
      ax += al * bf2f((unsigned short)(uu & 0xffffu));
      ay += al * bf2f((unsigned short)(uu >> 16));
    }
    nred[g * 128 + d2 * 2] = ax;
    nred[g * 128 + d2 * 2 + 1] = ay;
    __syncthreads();
    if (tid < 128) nhat[tid] = nred[tid] + nred[128 + tid] + nred[256 + tid] + nred[384 + tid];
    __syncthreads();
  }
  // ---- pass 4: logits = tok . n_hat + bias ----
  for (int li = 0; li < 8; ++li) {
    int l = li * 256 + tid;
    const uint4* rowp = (const uint4*)&tokpad[((size_t)b * LP + PAD + l) * 128];
    float s = 0.f;
    #pragma unroll
    for (int jj = 0; jj < 16; ++jj) {
      uint4 uu = rowp[jj];
      s += bf2f((unsigned short)(uu.x & 0xffffu)) * nhat[jj*8+0]
         + bf2f((unsigned short)(uu.x >> 16))     * nhat[jj*8+1]
         + bf2f((unsigned short)(uu.y & 0xffffu)) * nhat[jj*8+2]
         + bf2f((unsigned short)(uu.y >> 16))     * nhat[jj*8+3]
         + bf2f((unsigned short)(uu.z & 0xffffu)) * nhat[jj*8+4]
         + bf2f((unsigned short)(uu.z >> 16))     * nhat[jj*8+5]
         + bf2f((unsigned short)(uu.w & 0xffffu)) * nhat[jj*8+6]
         + bf2f((unsigned short)(uu.w >> 16))     * nhat[jj*8+7];
    }
    l_lds[l] = s + biasg[b * L_ + l];
  }
  __syncthreads();
  // ---- pass 5: final softmax -> out ----
  {
    float mx = -1e30f;
    for (int i = tid; i < 2048; i += 256) mx = fmaxf(mx, l_lds[i]);
    #pragma unroll
    for (int msk = 1; msk < 64; msk <<= 1) mx = fmaxf(mx, __shfl_xor(mx, msk));
    __syncthreads();
    if (lane == 0) red[wave] = mx;
    __syncthreads();
    mx = fmaxf(fmaxf(red[0], red[1]), fmaxf(red[2], red[3]));
    float sm = 0.f;
    for (int i = tid; i < 2048; i += 256) sm += __expf(l_lds[i] - mx);
    #pragma unroll
    for (int msk = 1; msk < 64; msk <<= 1) sm += __shfl_xor(sm, msk);
    __syncthreads();
    if (lane == 0) red[wave] = sm;
    __syncthreads();
    sm = red[0] + red[1] + red[2] + red[3];
    float inv = 1.f / sm;
    for (int i = tid; i < 2048; i += 256) out[b * L_ + i] = __expf(l_lds[i] - mx) * inv;
  }
}

// ---------------------------------------------------------------------------
extern "C" void kernel_launch(void* const* d_in, const int* in_sizes, int n_in,
                              void* d_out, int out_size, void* d_ws, size_t ws_size,
                              hipStream_t stream) {
  const int*   code = (const int*)d_in[0];
  const float* E    = (const float*)d_in[1];
  const float* bt   = (const float*)d_in[2];
  const float* Wx   = (const float*)d_in[3];
  const float* Wh   = (const float*)d_in[4];
  const float* bg   = (const float*)d_in[5];
  const float* c1w  = (const float*)d_in[6];
  const float* c1b  = (const float*)d_in[7];
  const float* c2w  = (const float*)d_in[8];
  const float* c2b  = (const float*)d_in[9];
  const float* c3w  = (const float*)d_in[10];
  const float* c3b  = (const float*)d_in[11];
  char* ws = (char*)d_ws;
  unsigned short* tokpad = (unsigned short*)(ws);               // 33,685,504 B
  unsigned short* l1pad  = (unsigned short*)(ws + 33685504);    // 16,842,752 B
  unsigned short* xproj  = (unsigned short*)(ws + 50528256);    // 50,331,648 B
  unsigned short* c2o    = (unsigned short*)(ws + 100859904);   // 16,777,216 B
  unsigned short* WxT    = (unsigned short*)(ws + 117637120);   //     49,152 B
  unsigned short* c1wT   = (unsigned short*)(ws + 117686272);   //    131,072 B
  unsigned short* c2wT   = (unsigned short*)(ws + 117817344);   //     65,536 B
  float*          htp    = (float*)(ws + 117882880);            //     16,384 B
  float*          biasg  = (float*)(ws + 117899264);            //    524,288 B
  // total ws use: 118,423,552 B

  k_prep <<<9232, 256, 0, stream>>>(code, E, bt, Wx, c1w, c2w, tokpad, l1pad, WxT, c1wT, c2wT, biasg);
  k_xproj<<<1024, 256, 0, stream>>>(tokpad, WxT, bg, xproj);
  k_scan <<<64, 192, 0, stream>>>(xproj, Wh, bg, htp);
  k_conv1<<<1024, 256, 0, stream>>>(tokpad, c1wT, c1b, l1pad);
  k_conv2<<<1024, 256, 0, stream>>>(l1pad, c2wT, c2b, c2o);
  k_final<<<64, 256, 0, stream>>>(tokpad, c2o, htp, c3w, c3b, biasg, (float*)d_out);
}

// Round 6
// 1699.002 us; speedup vs baseline: 1.4057x; 1.0287x over previous
//
#include <hip/hip_runtime.h>

#define B_ 64
#define L_ 2048
#define D_ 128
#define LP 2056   // padded rows per batch (3 left, 5 right incl. alignment)
#define PAD 3     // SAME-pad left for W=8

typedef __attribute__((ext_vector_type(8))) short short8;
typedef __attribute__((ext_vector_type(4))) float f32x4;

static __device__ __forceinline__ float bf2f(unsigned short u) {
  return __uint_as_float(((unsigned int)u) << 16);
}
static __device__ __forceinline__ unsigned short f2bf(float f) {
  unsigned int x = __float_as_uint(f);
  unsigned int r = (x + 0x7fffu + ((x >> 16) & 1u)) >> 16;  // RNE
  return (unsigned short)r;
}

// ---------------------------------------------------------------------------
// K0: gather tok -> bf16 padded [B,LP,128]; zero l1pad's pad rows; gather bias;
//     transpose weights to bf16 [n][k] layouts for MFMA B-fragments.
// ---------------------------------------------------------------------------
__global__ __launch_bounds__(256) void k_prep(
    const int* __restrict__ code, const float* __restrict__ E,
    const float* __restrict__ bias_table, const float* __restrict__ Wx,
    const float* __restrict__ c1w, const float* __restrict__ c2w,
    unsigned short* __restrict__ tokpad, unsigned short* __restrict__ l1pad,
    unsigned short* __restrict__ WxT, unsigned short* __restrict__ c1wT,
    unsigned short* __restrict__ c2wT, float* __restrict__ biasg)
{
  int id = blockIdx.x * 256 + threadIdx.x;
  const int N0 = B_ * LP * 16;            // tokpad in uint4 (8 bf16) chunks
  if (id < N0) {
    int b = id / (LP * 16); int rem = id % (LP * 16);
    int row = rem >> 4, c8 = rem & 15;
    uint4 o = {0u,0u,0u,0u};
    if (row >= PAD && row < PAD + L_) {
      int cd = code[b * L_ + (row - PAD)];
      const float4* e = (const float4*)(E + (size_t)cd * D_ + c8 * 8);
      float4 e0 = e[0], e1 = e[1];
      o.x = f2bf(e0.x) | ((unsigned int)f2bf(e0.y) << 16);
      o.y = f2bf(e0.z) | ((unsigned int)f2bf(e0.w) << 16);
      o.z = f2bf(e1.x) | ((unsigned int)f2bf(e1.y) << 16);
      o.w = f2bf(e1.z) | ((unsigned int)f2bf(e1.w) << 16);
    }
    ((uint4*)tokpad)[id] = o;
    return;
  }
  id -= N0;
  const int N1 = B_ * 8 * 8;              // l1pad pad rows (8 rows x 8 chunks)
  if (id < N1) {
    int b = id >> 6; int rem = id & 63; int ri = rem >> 3, c8 = rem & 7;
    int row = ri < 3 ? ri : (L_ + ri);    // 0,1,2, 2051..2055
    uint4 z = {0u,0u,0u,0u};
    ((uint4*)l1pad)[(b * LP + row) * 8 + c8] = z;
    return;
  }
  id -= N1;
  const int N2 = B_ * L_;
  if (id < N2) { biasg[id] = bias_table[code[id]]; return; }
  id -= N2;
  const int N3 = 192 * 128;               // WxT[c][d]
  if (id < N3) { int c = id >> 7, d = id & 127; WxT[id] = f2bf(Wx[d * 192 + c]); return; }
  id -= N3;
  const int N4 = 8 * 64 * 128;            // c1wT[w][c][d]
  if (id < N4) {
    int w = id >> 13, c = (id >> 7) & 63, d = id & 127;
    c1wT[id] = f2bf(c1w[(w * 128 + d) * 64 + c]); return;
  }
  id -= N4;
  const int N5 = 8 * 64 * 64;             // c2wT[w][c][d]
  if (id < N5) {
    int w = id >> 12, c = (id >> 6) & 63, d = id & 63;
    c2wT[id] = f2bf(c2w[(w * 64 + d) * 64 + c]);
  }
}

// ---------------------------------------------------------------------------
// K1: x_proj = tok @ Wx + b_gru[0]  -> bf16 [B,L,192]   (MFMA 16x16x32 bf16)
// ---------------------------------------------------------------------------
__global__ __launch_bounds__(256) void k_xproj(
    const unsigned short* __restrict__ tokpad, const unsigned short* __restrict__ WxT,
    const float* __restrict__ bg, unsigned short* __restrict__ xproj)
{
  __shared__ __align__(16) unsigned short At[128 * 136];
  __shared__ __align__(16) unsigned short Bt[192 * 136];
  int b = blockIdx.x >> 4;
  int l0 = (blockIdx.x & 15) << 7;
  int tid = threadIdx.x;
  for (int i = tid; i < 128 * 16; i += 256) {
    int row = i >> 4, c8 = i & 15;
    uint4 v = ((const uint4*)tokpad)[(b * LP + PAD + l0 + row) * 16 + c8];
    *((uint4*)&At[row * 136 + c8 * 8]) = v;
  }
  for (int i = tid; i < 192 * 16; i += 256) {
    int row = i >> 4, c8 = i & 15;
    uint4 v = ((const uint4*)WxT)[i];
    *((uint4*)&Bt[row * 136 + c8 * 8]) = v;
  }
  __syncthreads();
  int wave = tid >> 6, lane = tid & 63;
  int m = lane & 15, q = lane >> 4;
  f32x4 acc[2][12];
  #pragma unroll
  for (int mt = 0; mt < 2; ++mt)
    #pragma unroll
    for (int nt = 0; nt < 12; ++nt) acc[mt][nt] = (f32x4){0.f,0.f,0.f,0.f};
  #pragma unroll
  for (int ks = 0; ks < 4; ++ks) {
    int kof = ks * 32 + q * 8;
    short8 a[2], bb[12];
    #pragma unroll
    for (int mt = 0; mt < 2; ++mt)
      a[mt] = *(const short8*)&At[(wave * 32 + mt * 16 + m) * 136 + kof];
    #pragma unroll
    for (int nt = 0; nt < 12; ++nt)
      bb[nt] = *(const short8*)&Bt[(nt * 16 + m) * 136 + kof];
    #pragma unroll
    for (int mt = 0; mt < 2; ++mt)
      #pragma unroll
      for (int nt = 0; nt < 12; ++nt)
        acc[mt][nt] = __builtin_amdgcn_mfma_f32_16x16x32_bf16(a[mt], bb[nt], acc[mt][nt], 0, 0, 0);
  }
  #pragma unroll
  for (int mt = 0; mt < 2; ++mt) {
    int lrow = l0 + wave * 32 + mt * 16 + q * 4;
    #pragma unroll
    for (int nt = 0; nt < 12; ++nt) {
      int c = nt * 16 + m;                 // C col = lane&15
      float b0 = bg[c];
      #pragma unroll
      for (int r = 0; r < 4; ++r)
        xproj[(size_t)(b * L_ + lrow + r) * 192 + c] = f2bf(acc[mt][nt][r] + b0);
    }
  }
}

// ---------------------------------------------------------------------------
// K2: conv1 = relu(conv8(tok,c1w)+c1b) -> bf16 l1pad rows [3,2051)
// ---------------------------------------------------------------------------
__global__ __launch_bounds__(256) void k_conv1(
    const unsigned short* __restrict__ tokpad, const unsigned short* __restrict__ c1wT,
    const float* __restrict__ c1b, unsigned short* __restrict__ l1pad)
{
  __shared__ __align__(16) unsigned short At[135 * 136];
  __shared__ __align__(16) unsigned short Bw[64 * 136];
  int b = blockIdx.x >> 4;
  int l0 = (blockIdx.x & 15) << 7;
  int tid = threadIdx.x;
  for (int i = tid; i < 135 * 16; i += 256) {
    int row = i >> 4, c8 = i & 15;
    uint4 v = ((const uint4*)tokpad)[(b * LP + l0 + row) * 16 + c8];
    *((uint4*)&At[row * 136 + c8 * 8]) = v;
  }
  int wave = tid >> 6, lane = tid & 63;
  int m = lane & 15, q = lane >> 4;
  f32x4 acc[2][4];
  #pragma unroll
  for (int mt = 0; mt < 2; ++mt)
    #pragma unroll
    for (int nt = 0; nt < 4; ++nt) acc[mt][nt] = (f32x4){0.f,0.f,0.f,0.f};
  for (int w = 0; w < 8; ++w) {
    __syncthreads();                       // covers At (w=0) and Bw reuse
    for (int i = tid; i < 64 * 16; i += 256) {
      int row = i >> 4, c8 = i & 15;
      uint4 v = ((const uint4*)c1wT)[(w * 64 + row) * 16 + c8];
      *((uint4*)&Bw[row * 136 + c8 * 8]) = v;
    }
    __syncthreads();
    #pragma unroll
    for (int ks = 0; ks < 4; ++ks) {
      int kof = ks * 32 + q * 8;
      short8 a[2], bb[4];
      #pragma unroll
      for (int mt = 0; mt < 2; ++mt)
        a[mt] = *(const short8*)&At[(wave * 32 + mt * 16 + m + w) * 136 + kof];
      #pragma unroll
      for (int nt = 0; nt < 4; ++nt)
        bb[nt] = *(const short8*)&Bw[(nt * 16 + m) * 136 + kof];
      #pragma unroll
      for (int mt = 0; mt < 2; ++mt)
        #pragma unroll
        for (int nt = 0; nt < 4; ++nt)
          acc[mt][nt] = __builtin_amdgcn_mfma_f32_16x16x32_bf16(a[mt], bb[nt], acc[mt][nt], 0, 0, 0);
    }
  }
  #pragma unroll
  for (int mt = 0; mt < 2; ++mt) {
    int lrow = l0 + wave * 32 + mt * 16 + q * 4;
    #pragma unroll
    for (int nt = 0; nt < 4; ++nt) {
      int c = nt * 16 + m;
      float bias = c1b[c];
      #pragma unroll
      for (int r = 0; r < 4; ++r) {
        float v = fmaxf(acc[mt][nt][r] + bias, 0.f);
        l1pad[(size_t)(b * LP + PAD + lrow + r) * 64 + c] = f2bf(v);
      }
    }
  }
}

// ---------------------------------------------------------------------------
// K3: conv2 (+c2b, pre h_t multiply) -> bf16 c2out [B,L,64]
// ---------------------------------------------------------------------------
__global__ __launch_bounds__(256) void k_conv2(
    const unsigned short* __restrict__ l1pad, const unsigned short* __restrict__ c2wT,
    const float* __restrict__ c2b, unsigned short* __restrict__ c2o)
{
  __shared__ __align__(16) unsigned short At[135 * 72];
  __shared__ __align__(16) unsigned short Bw[64 * 72];
  int b = blockIdx.x >> 4;
  int l0 = (blockIdx.x & 15) << 7;
  int tid = threadIdx.x;
  for (int i = tid; i < 135 * 8; i += 256) {
    int row = i >> 3, c8 = i & 7;
    uint4 v = ((const uint4*)l1pad)[(b * LP + l0 + row) * 8 + c8];
    *((uint4*)&At[row * 72 + c8 * 8]) = v;
  }
  int wave = tid >> 6, lane = tid & 63;
  int m = lane & 15, q = lane >> 4;
  f32x4 acc[2][4];
  #pragma unroll
  for (int mt = 0; mt < 2; ++mt)
    #pragma unroll
    for (int nt = 0; nt < 4; ++nt) acc[mt][nt] = (f32x4){0.f,0.f,0.f,0.f};
  for (int w = 0; w < 8; ++w) {
    __syncthreads();
    for (int i = tid; i < 64 * 8; i += 256) {
      int row = i >> 3, c8 = i & 7;
      uint4 v = ((const uint4*)c2wT)[(w * 64 + row) * 8 + c8];
      *((uint4*)&Bw[row * 72 + c8 * 8]) = v;
    }
    __syncthreads();
    #pragma unroll
    for (int ks = 0; ks < 2; ++ks) {
      int kof = ks * 32 + q * 8;
      short8 a[2], bb[4];
      #pragma unroll
      for (int mt = 0; mt < 2; ++mt)
        a[mt] = *(const short8*)&At[(wave * 32 + mt * 16 + m + w) * 72 + kof];
      #pragma unroll
      for (int nt = 0; nt < 4; ++nt)
        bb[nt] = *(const short8*)&Bw[(nt * 16 + m) * 72 + kof];
      #pragma unroll
      for (int mt = 0; mt < 2; ++mt)
        #pragma unroll
        for (int nt = 0; nt < 4; ++nt)
          acc[mt][nt] = __builtin_amdgcn_mfma_f32_16x16x32_bf16(a[mt], bb[nt], acc[mt][nt], 0, 0, 0);
    }
  }
  #pragma unroll
  for (int mt = 0; mt < 2; ++mt) {
    int lrow = l0 + wave * 32 + mt * 16 + q * 4;
    #pragma unroll
    for (int nt = 0; nt < 4; ++nt) {
      int c = nt * 16 + m;
      float bias = c2b[c];
      #pragma unroll
      for (int r = 0; r < 4; ++r)
        c2o[(size_t)(b * L_ + lrow + r) * 64 + c] = f2bf(acc[mt][nt][r] + bias);
    }
  }
}

// ---------------------------------------------------------------------------
// K4 v6: GRU scan = R2 structure + occupancy cap. Root cause of R1/R2/R5's
// VGPR=44: the backend spills registers to hit MAX achievable occupancy
// (192-thr WG -> 10 WG/CU -> 8 waves/EU -> 64-reg budget). Fix: declare
// occupancy 1 wave/EU via amdgpu_waves_per_eu(1,1) (512-reg budget) AND a
// 56 KB LDS block as hardware backstop (max 2 WG/CU -> <=2 waves/EU).
// We launch 64 WGs over 256 CUs, so real occupancy is unchanged.
// ---------------------------------------------------------------------------
__global__ __launch_bounds__(192)
__attribute__((amdgpu_waves_per_eu(1, 1)))
void k_scan(
    const unsigned short* __restrict__ xproj, const float* __restrict__ Wh,
    const float* __restrict__ bg, float* __restrict__ h_t)
{
  // 14336 floats = 56 KB: h_lds = [0,64), s_z = [64,128), s_r = [128,192).
  __shared__ __align__(16) float lds_pool[14336];
  float* h_lds = lds_pool;
  float* s_z   = lds_pool + 64;
  float* s_r   = lds_pool + 128;

  int b = blockIdx.x;
  int tid = threadIdx.x;
  int wave = tid >> 6, j = tid & 63;
  int o = wave * 64 + j;                  // output column 0..191

#define DECL_W(i) float4 w##i = {Wh[(4*i+0)*192+o], Wh[(4*i+1)*192+o], \
                                 Wh[(4*i+2)*192+o], Wh[(4*i+3)*192+o]};
  DECL_W(0)  DECL_W(1)  DECL_W(2)  DECL_W(3)
  DECL_W(4)  DECL_W(5)  DECL_W(6)  DECL_W(7)
  DECL_W(8)  DECL_W(9)  DECL_W(10) DECL_W(11)
  DECL_W(12) DECL_W(13) DECL_W(14) DECL_W(15)
#undef DECL_W
  // Opacity pin: asm outputs cannot be rematerialized from memory.
#define OPAQ(i) asm volatile("" : "+v"(w##i.x), "+v"(w##i.y), "+v"(w##i.z), "+v"(w##i.w));
  OPAQ(0)  OPAQ(1)  OPAQ(2)  OPAQ(3)
  OPAQ(4)  OPAQ(5)  OPAQ(6)  OPAQ(7)
  OPAQ(8)  OPAQ(9)  OPAQ(10) OPAQ(11)
  OPAQ(12) OPAQ(13) OPAQ(14) OPAQ(15)
#undef OPAQ
  float bias = bg[192 + o];               // b_gru[1][o]

  if (wave == 2) h_lds[j] = 0.f;
  float h_old = 0.f;                      // wave2's private copy of h[j]

  const unsigned short* xp = xproj + (size_t)b * L_ * 192 + o;
  unsigned short x0 = xp[0];
  unsigned short x1 = xp[192];
  const float4* hl4 = (const float4*)h_lds;

  for (int t = 0; t < L_; ++t) {
    __syncthreads();                      // barrier A: h_lds ready, s_* free
    int tn = (t + 2 < L_) ? t + 2 : (L_ - 1);
    unsigned short x2 = xp[(size_t)tn * 192];

    float a0 = bias, a1 = 0.f, a2 = 0.f, a3 = 0.f;
#define ACC_W(i) { float4 h4 = hl4[i]; \
    a0 = fmaf(h4.x, w##i.x, a0); a1 = fmaf(h4.y, w##i.y, a1); \
    a2 = fmaf(h4.z, w##i.z, a2); a3 = fmaf(h4.w, w##i.w, a3); }
    ACC_W(0)  ACC_W(1)  ACC_W(2)  ACC_W(3)
    ACC_W(4)  ACC_W(5)  ACC_W(6)  ACC_W(7)
    ACC_W(8)  ACC_W(9)  ACC_W(10) ACC_W(11)
    ACC_W(12) ACC_W(13) ACC_W(14) ACC_W(15)
#undef ACC_W
    float s = (a0 + a1) + (a2 + a3);      // recurrent preact for column o
    float xv = bf2f(x0);

    if (wave == 0)      s_z[j] = 1.f / (1.f + __expf(-(xv + s)));   // z
    else if (wave == 1) s_r[j] = 1.f / (1.f + __expf(-(xv + s)));   // r
    __syncthreads();                      // barrier B: gates visible, h_lds free
    if (wave == 2) {
      float z = s_z[j], r = s_r[j];
      float e2 = __expf(-2.f * (xv + r * s));
      float hh = fmaf(2.f, __frcp_rn(1.f + e2), -1.f); // tanh
      h_old = z * h_old + (1.f - z) * hh;
      h_lds[j] = h_old;
    }
    x0 = x1; x1 = x2;
  }
  if (wave == 2) h_t[b * 64 + j] = h_old;
}

// ---------------------------------------------------------------------------
// K5: per-batch tail: L2=c2o*h_t -> l2norm -> conv3 -> softmax alpha ->
//     n_hat = sum alpha*tok -> logits = tok.n_hat + bias -> softmax -> out
// ---------------------------------------------------------------------------
__global__ __launch_bounds__(256) void k_final(
    const unsigned short* __restrict__ tokpad, const unsigned short* __restrict__ c2o,
    const float* __restrict__ h_t, const float* __restrict__ c3w,
    const float* __restrict__ c3b, const float* __restrict__ biasg,
    float* __restrict__ out)
{
  __shared__ float Lf[71 * 65];
  __shared__ float a_lds[2048];
  __shared__ float l_lds[2048];
  __shared__ float red[256];
  __shared__ float nred[512];
  __shared__ float nhat[128];
  __shared__ float ht[64];
  __shared__ float c3[512];
  int b = blockIdx.x, tid = threadIdx.x, lane = tid & 63, wave = tid >> 6;
  if (tid < 64) ht[tid] = h_t[b * 64 + tid];
  for (int i = tid; i < 512; i += 256) c3[i] = c3w[i];
  float c3bias = c3b[0];
  __syncthreads();
  // ---- pass 1: a_logits via normalized features + conv3 (tiles of 64 l) ----
  for (int tile = 0; tile < 32; ++tile) {
    int lt = tile << 6;
    for (int i0 = wave; i0 < 71; i0 += 4) {
      int l = lt - 3 + i0;
      float v = 0.f;
      if (l >= 0 && l < L_) v = bf2f(c2o[((size_t)b * L_ + l) * 64 + lane]) * ht[lane];
      float ss = v * v;
      #pragma unroll
      for (int msk = 1; msk < 64; msk <<= 1) ss += __shfl_xor(ss, msk);
      Lf[i0 * 65 + lane] = v * rsqrtf(ss + 1e-12f);
    }
    __syncthreads();
    {
      int u = lane, part = wave;
      float p = 0.f;
      #pragma unroll
      for (int w = 0; w < 8; ++w)
        #pragma unroll
        for (int cc = 0; cc < 16; ++cc) {
          int c = part * 16 + cc;
          p += Lf[(u + w) * 65 + c] * c3[w * 64 + c];
        }
      red[tid] = p;
    }
    __syncthreads();
    if (tid < 64) a_lds[lt + tid] = red[tid] + red[64 + tid] + red[128 + tid] + red[192 + tid] + c3bias;
    __syncthreads();
  }
  // ---- pass 2: softmax alpha over 2048 ----
  {
    float mx = -1e30f;
    for (int i = tid; i < 2048; i += 256) mx = fmaxf(mx, a_lds[i]);
    #pragma unroll
    for (int msk = 1; msk < 64; msk <<= 1) mx = fmaxf(mx, __shfl_xor(mx, msk));
    if (lane == 0) red[wave] = mx;
    __syncthreads();
    mx = fmaxf(fmaxf(red[0], red[1]), fmaxf(red[2], red[3]));
    float sm = 0.f;
    for (int i = tid; i < 2048; i += 256) sm += __expf(a_lds[i] - mx);
    #pragma unroll
    for (int msk = 1; msk < 64; msk <<= 1) sm += __shfl_xor(sm, msk);
    __syncthreads();
    if (lane == 0) red[wave] = sm;
    __syncthreads();
    sm = red[0] + red[1] + red[2] + red[3];
    float inv = 1.f / sm;
    for (int i = tid; i < 2048; i += 256) a_lds[i] = __expf(a_lds[i] - mx) * inv;
    __syncthreads();
  }
  // ---- pass 3: n_hat[128] = sum_l alpha_l * tok[l][:] ----
  {
    int d2 = tid & 63, g = tid >> 6;
    float ax = 0.f, ay = 0.f;
    for (int l = g; l < L_; l += 4) {
      unsigned int uu = *(const unsigned int*)&tokpad[((size_t)b * LP + PAD + l) * 128 + d2 * 2];
      float al = a_lds[l];
      ax += al * bf2f((unsigned short)(uu & 0xffffu));
      ay += al * bf2f((unsigned short)(uu >> 16));
    }
    nred[g * 128 + d2 * 2] = ax;
    nred[g * 128 + d2 * 2 + 1] = ay;
    __syncthreads();
    if (tid < 128) nhat[tid] = nred[tid] + nred[128 + tid] + nred[256 + tid] + nred[384 + tid];
    __syncthreads();
  }
  // ---- pass 4: logits = tok . n_hat + bias ----
  for (int li = 0; li < 8; ++li) {
    int l = li * 256 + tid;
    const uint4* rowp = (const uint4*)&tokpad[((size_t)b * LP + PAD + l) * 128];
    float s = 0.f;
    #pragma unroll
    for (int jj = 0; jj < 16; ++jj) {
      uint4 uu = rowp[jj];
      s += bf2f((unsigned short)(uu.x & 0xffffu)) * nhat[jj*8+0]
         + bf2f((unsigned short)(uu.x >> 16))     * nhat[jj*8+1]
         + bf2f((unsigned short)(uu.y & 0xffffu)) * nhat[jj*8+2]
         + bf2f((unsigned short)(uu.y >> 16))     * nhat[jj*8+3]
         + bf2f((unsigned short)(uu.z & 0xffffu)) * nhat[jj*8+4]
         + bf2f((unsigned short)(uu.z >> 16))     * nhat[jj*8+5]
         + bf2f((unsigned short)(uu.w & 0xffffu)) * nhat[jj*8+6]
         + bf2f((unsigned short)(uu.w >> 16))     * nhat[jj*8+7];
    }
    l_lds[l] = s + biasg[b * L_ + l];
  }
  __syncthreads();
  // ---- pass 5: final softmax -> out ----
  {
    float mx = -1e30f;
    for (int i = tid; i < 2048; i += 256) mx = fmaxf(mx, l_lds[i]);
    #pragma unroll
    for (int msk = 1; msk < 64; msk <<= 1) mx = fmaxf(mx, __shfl_xor(mx, msk));
    __syncthreads();
    if (lane == 0) red[wave] = mx;
    __syncthreads();
    mx = fmaxf(fmaxf(red[0], red[1]), fmaxf(red[2], red[3]));
    float sm = 0.f;
    for (int i = tid; i < 2048; i += 256) sm += __expf(l_lds[i] - mx);
    #pragma unroll
    for (int msk = 1; msk < 64; msk <<= 1) sm += __shfl_xor(sm, msk);
    __syncthreads();
    if (lane == 0) red[wave] = sm;
    __syncthreads();
    sm = red[0] + red[1] + red[2] + red[3];
    float inv = 1.f / sm;
    for (int i = tid; i < 2048; i += 256) out[b * L_ + i] = __expf(l_lds[i] - mx) * inv;
  }
}

// ---------------------------------------------------------------------------
extern "C" void kernel_launch(void* const* d_in, const int* in_sizes, int n_in,
                              void* d_out, int out_size, void* d_ws, size_t ws_size,
                              hipStream_t stream) {
  const int*   code = (const int*)d_in[0];
  const float* E    = (const float*)d_in[1];
  const float* bt   = (const float*)d_in[2];
  const float* Wx   = (const float*)d_in[3];
  const float* Wh   = (const float*)d_in[4];
  const float* bg   = (const float*)d_in[5];
  const float* c1w  = (const float*)d_in[6];
  const float* c1b  = (const float*)d_in[7];
  const float* c2w  = (const float*)d_in[8];
  const float* c2b  = (const float*)d_in[9];
  const float* c3w  = (const float*)d_in[10];
  const float* c3b  = (const float*)d_in[11];
  char* ws = (char*)d_ws;
  unsigned short* tokpad = (unsigned short*)(ws);               // 33,685,504 B
  unsigned short* l1pad  = (unsigned short*)(ws + 33685504);    // 16,842,752 B
  unsigned short* xproj  = (unsigned short*)(ws + 50528256);    // 50,331,648 B
  unsigned short* c2o    = (unsigned short*)(ws + 100859904);   // 16,777,216 B
  unsigned short* WxT    = (unsigned short*)(ws + 117637120);   //     49,152 B
  unsigned short* c1wT   = (unsigned short*)(ws + 117686272);   //    131,072 B
  unsigned short* c2wT   = (unsigned short*)(ws + 117817344);   //     65,536 B
  float*          htp    = (float*)(ws + 117882880);            //     16,384 B
  float*          biasg  = (float*)(ws + 117899264);            //    524,288 B
  // total ws use: 118,423,552 B

  k_prep <<<9232, 256, 0, stream>>>(code, E, bt, Wx, c1w, c2w, tokpad, l1pad, WxT, c1wT, c2wT, biasg);
  k_xproj<<<1024, 256, 0, stream>>>(tokpad, WxT, bg, xproj);
  k_scan <<<64, 192, 0, stream>>>(xproj, Wh, bg, htp);
  k_conv1<<<1024, 256, 0, stream>>>(tokpad, c1wT, c1b, l1pad);
  k_conv2<<<1024, 256, 0, stream>>>(l1pad, c2wT, c2b, c2o);
  k_final<<<64, 256, 0, stream>>>(tokpad, c2o, htp, c3w, c3b, biasg, (float*)d_out);
}

// Round 7
// 1647.087 us; speedup vs baseline: 1.4501x; 1.0315x over previous
//
#include <hip/hip_runtime.h>

#define B_ 64
#define L_ 2048
#define D_ 128
#define LP 2056   // padded rows per batch (3 left, 5 right incl. alignment)
#define PAD 3     // SAME-pad left for W=8

typedef __attribute__((ext_vector_type(8))) short short8;
typedef __attribute__((ext_vector_type(4))) float f32x4;
typedef __attribute__((ext_vector_type(4))) unsigned short us4;

static __device__ __forceinline__ float bf2f(unsigned short u) {
  return __uint_as_float(((unsigned int)u) << 16);
}
static __device__ __forceinline__ unsigned short f2bf(float f) {
  unsigned int x = __float_as_uint(f);
  unsigned int r = (x + 0x7fffu + ((x >> 16) & 1u)) >> 16;  // RNE
  return (unsigned short)r;
}

// ---------------------------------------------------------------------------
// K0: gather tok -> bf16 padded [B,LP,128]; zero l1pad's pad rows; gather bias;
//     transpose weights to bf16 [n][k] layouts for MFMA B-fragments.
// ---------------------------------------------------------------------------
__global__ __launch_bounds__(256) void k_prep(
    const int* __restrict__ code, const float* __restrict__ E,
    const float* __restrict__ bias_table, const float* __restrict__ Wx,
    const float* __restrict__ c1w, const float* __restrict__ c2w,
    unsigned short* __restrict__ tokpad, unsigned short* __restrict__ l1pad,
    unsigned short* __restrict__ WxT, unsigned short* __restrict__ c1wT,
    unsigned short* __restrict__ c2wT, float* __restrict__ biasg)
{
  int id = blockIdx.x * 256 + threadIdx.x;
  const int N0 = B_ * LP * 16;            // tokpad in uint4 (8 bf16) chunks
  if (id < N0) {
    int b = id / (LP * 16); int rem = id % (LP * 16);
    int row = rem >> 4, c8 = rem & 15;
    uint4 o = {0u,0u,0u,0u};
    if (row >= PAD && row < PAD + L_) {
      int cd = code[b * L_ + (row - PAD)];
      const float4* e = (const float4*)(E + (size_t)cd * D_ + c8 * 8);
      float4 e0 = e[0], e1 = e[1];
      o.x = f2bf(e0.x) | ((unsigned int)f2bf(e0.y) << 16);
      o.y = f2bf(e0.z) | ((unsigned int)f2bf(e0.w) << 16);
      o.z = f2bf(e1.x) | ((unsigned int)f2bf(e1.y) << 16);
      o.w = f2bf(e1.z) | ((unsigned int)f2bf(e1.w) << 16);
    }
    ((uint4*)tokpad)[id] = o;
    return;
  }
  id -= N0;
  const int N1 = B_ * 8 * 8;              // l1pad pad rows (8 rows x 8 chunks)
  if (id < N1) {
    int b = id >> 6; int rem = id & 63; int ri = rem >> 3, c8 = rem & 7;
    int row = ri < 3 ? ri : (L_ + ri);    // 0,1,2, 2051..2055
    uint4 z = {0u,0u,0u,0u};
    ((uint4*)l1pad)[(b * LP + row) * 8 + c8] = z;
    return;
  }
  id -= N1;
  const int N2 = B_ * L_;
  if (id < N2) { biasg[id] = bias_table[code[id]]; return; }
  id -= N2;
  const int N3 = 192 * 128;               // WxT[c][d]
  if (id < N3) { int c = id >> 7, d = id & 127; WxT[id] = f2bf(Wx[d * 192 + c]); return; }
  id -= N3;
  const int N4 = 8 * 64 * 128;            // c1wT[w][c][d]
  if (id < N4) {
    int w = id >> 13, c = (id >> 7) & 63, d = id & 127;
    c1wT[id] = f2bf(c1w[(w * 128 + d) * 64 + c]); return;
  }
  id -= N4;
  const int N5 = 8 * 64 * 64;             // c2wT[w][c][d]
  if (id < N5) {
    int w = id >> 12, c = (id >> 6) & 63, d = id & 63;
    c2wT[id] = f2bf(c2w[(w * 64 + d) * 64 + c]);
  }
}

// ---------------------------------------------------------------------------
// K1: x_proj = tok @ Wx + b_gru[0] -> bf16 TRANSPOSED [B,192,L]
// (contiguous-in-time per gate column, so k_scan can load 16-step chunks
//  with dwordx4). C-fragment rows are 4 consecutive l -> one ushort4 store.
// ---------------------------------------------------------------------------
__global__ __launch_bounds__(256) void k_xproj(
    const unsigned short* __restrict__ tokpad, const unsigned short* __restrict__ WxT,
    const float* __restrict__ bg, unsigned short* __restrict__ xprojT)
{
  __shared__ __align__(16) unsigned short At[128 * 136];
  __shared__ __align__(16) unsigned short Bt[192 * 136];
  int b = blockIdx.x >> 4;
  int l0 = (blockIdx.x & 15) << 7;
  int tid = threadIdx.x;
  for (int i = tid; i < 128 * 16; i += 256) {
    int row = i >> 4, c8 = i & 15;
    uint4 v = ((const uint4*)tokpad)[(b * LP + PAD + l0 + row) * 16 + c8];
    *((uint4*)&At[row * 136 + c8 * 8]) = v;
  }
  for (int i = tid; i < 192 * 16; i += 256) {
    int row = i >> 4, c8 = i & 15;
    uint4 v = ((const uint4*)WxT)[i];
    *((uint4*)&Bt[row * 136 + c8 * 8]) = v;
  }
  __syncthreads();
  int wave = tid >> 6, lane = tid & 63;
  int m = lane & 15, q = lane >> 4;
  f32x4 acc[2][12];
  #pragma unroll
  for (int mt = 0; mt < 2; ++mt)
    #pragma unroll
    for (int nt = 0; nt < 12; ++nt) acc[mt][nt] = (f32x4){0.f,0.f,0.f,0.f};
  #pragma unroll
  for (int ks = 0; ks < 4; ++ks) {
    int kof = ks * 32 + q * 8;
    short8 a[2], bb[12];
    #pragma unroll
    for (int mt = 0; mt < 2; ++mt)
      a[mt] = *(const short8*)&At[(wave * 32 + mt * 16 + m) * 136 + kof];
    #pragma unroll
    for (int nt = 0; nt < 12; ++nt)
      bb[nt] = *(const short8*)&Bt[(nt * 16 + m) * 136 + kof];
    #pragma unroll
    for (int mt = 0; mt < 2; ++mt)
      #pragma unroll
      for (int nt = 0; nt < 12; ++nt)
        acc[mt][nt] = __builtin_amdgcn_mfma_f32_16x16x32_bf16(a[mt], bb[nt], acc[mt][nt], 0, 0, 0);
  }
  #pragma unroll
  for (int mt = 0; mt < 2; ++mt) {
    int lrow = l0 + wave * 32 + mt * 16 + q * 4;
    #pragma unroll
    for (int nt = 0; nt < 12; ++nt) {
      int c = nt * 16 + m;                 // C col = lane&15
      float b0 = bg[c];
      us4 val;
      val.x = f2bf(acc[mt][nt][0] + b0);
      val.y = f2bf(acc[mt][nt][1] + b0);
      val.z = f2bf(acc[mt][nt][2] + b0);
      val.w = f2bf(acc[mt][nt][3] + b0);
      *((us4*)&xprojT[((size_t)b * 192 + c) * L_ + lrow]) = val;
    }
  }
}

// ---------------------------------------------------------------------------
// K2: conv1 = relu(conv8(tok,c1w)+c1b) -> bf16 l1pad rows [3,2051)
// ---------------------------------------------------------------------------
__global__ __launch_bounds__(256) void k_conv1(
    const unsigned short* __restrict__ tokpad, const unsigned short* __restrict__ c1wT,
    const float* __restrict__ c1b, unsigned short* __restrict__ l1pad)
{
  __shared__ __align__(16) unsigned short At[135 * 136];
  __shared__ __align__(16) unsigned short Bw[64 * 136];
  int b = blockIdx.x >> 4;
  int l0 = (blockIdx.x & 15) << 7;
  int tid = threadIdx.x;
  for (int i = tid; i < 135 * 16; i += 256) {
    int row = i >> 4, c8 = i & 15;
    uint4 v = ((const uint4*)tokpad)[(b * LP + l0 + row) * 16 + c8];
    *((uint4*)&At[row * 136 + c8 * 8]) = v;
  }
  int wave = tid >> 6, lane = tid & 63;
  int m = lane & 15, q = lane >> 4;
  f32x4 acc[2][4];
  #pragma unroll
  for (int mt = 0; mt < 2; ++mt)
    #pragma unroll
    for (int nt = 0; nt < 4; ++nt) acc[mt][nt] = (f32x4){0.f,0.f,0.f,0.f};
  for (int w = 0; w < 8; ++w) {
    __syncthreads();                       // covers At (w=0) and Bw reuse
    for (int i = tid; i < 64 * 16; i += 256) {
      int row = i >> 4, c8 = i & 15;
      uint4 v = ((const uint4*)c1wT)[(w * 64 + row) * 16 + c8];
      *((uint4*)&Bw[row * 136 + c8 * 8]) = v;
    }
    __syncthreads();
    #pragma unroll
    for (int ks = 0; ks < 4; ++ks) {
      int kof = ks * 32 + q * 8;
      short8 a[2], bb[4];
      #pragma unroll
      for (int mt = 0; mt < 2; ++mt)
        a[mt] = *(const short8*)&At[(wave * 32 + mt * 16 + m + w) * 136 + kof];
      #pragma unroll
      for (int nt = 0; nt < 4; ++nt)
        bb[nt] = *(const short8*)&Bw[(nt * 16 + m) * 136 + kof];
      #pragma unroll
      for (int mt = 0; mt < 2; ++mt)
        #pragma unroll
        for (int nt = 0; nt < 4; ++nt)
          acc[mt][nt] = __builtin_amdgcn_mfma_f32_16x16x32_bf16(a[mt], bb[nt], acc[mt][nt], 0, 0, 0);
    }
  }
  #pragma unroll
  for (int mt = 0; mt < 2; ++mt) {
    int lrow = l0 + wave * 32 + mt * 16 + q * 4;
    #pragma unroll
    for (int nt = 0; nt < 4; ++nt) {
      int c = nt * 16 + m;
      float bias = c1b[c];
      #pragma unroll
      for (int r = 0; r < 4; ++r) {
        float v = fmaxf(acc[mt][nt][r] + bias, 0.f);
        l1pad[(size_t)(b * LP + PAD + lrow + r) * 64 + c] = f2bf(v);
      }
    }
  }
}

// ---------------------------------------------------------------------------
// K3: conv2 (+c2b, pre h_t multiply) -> bf16 c2out [B,L,64]
// ---------------------------------------------------------------------------
__global__ __launch_bounds__(256) void k_conv2(
    const unsigned short* __restrict__ l1pad, const unsigned short* __restrict__ c2wT,
    const float* __restrict__ c2b, unsigned short* __restrict__ c2o)
{
  __shared__ __align__(16) unsigned short At[135 * 72];
  __shared__ __align__(16) unsigned short Bw[64 * 72];
  int b = blockIdx.x >> 4;
  int l0 = (blockIdx.x & 15) << 7;
  int tid = threadIdx.x;
  for (int i = tid; i < 135 * 8; i += 256) {
    int row = i >> 3, c8 = i & 7;
    uint4 v = ((const uint4*)l1pad)[(b * LP + l0 + row) * 8 + c8];
    *((uint4*)&At[row * 72 + c8 * 8]) = v;
  }
  int wave = tid >> 6, lane = tid & 63;
  int m = lane & 15, q = lane >> 4;
  f32x4 acc[2][4];
  #pragma unroll
  for (int mt = 0; mt < 2; ++mt)
    #pragma unroll
    for (int nt = 0; nt < 4; ++nt) acc[mt][nt] = (f32x4){0.f,0.f,0.f,0.f};
  for (int w = 0; w < 8; ++w) {
    __syncthreads();
    for (int i = tid; i < 64 * 8; i += 256) {
      int row = i >> 3, c8 = i & 7;
      uint4 v = ((const uint4*)c2wT)[(w * 64 + row) * 8 + c8];
      *((uint4*)&Bw[row * 72 + c8 * 8]) = v;
    }
    __syncthreads();
    #pragma unroll
    for (int ks = 0; ks < 2; ++ks) {
      int kof = ks * 32 + q * 8;
      short8 a[2], bb[4];
      #pragma unroll
      for (int mt = 0; mt < 2; ++mt)
        a[mt] = *(const short8*)&At[(wave * 32 + mt * 16 + m + w) * 72 + kof];
      #pragma unroll
      for (int nt = 0; nt < 4; ++nt)
        bb[nt] = *(const short8*)&Bw[(nt * 16 + m) * 72 + kof];
      #pragma unroll
      for (int mt = 0; mt < 2; ++mt)
        #pragma unroll
        for (int nt = 0; nt < 4; ++nt)
          acc[mt][nt] = __builtin_amdgcn_mfma_f32_16x16x32_bf16(a[mt], bb[nt], acc[mt][nt], 0, 0, 0);
    }
  }
  #pragma unroll
  for (int mt = 0; mt < 2; ++mt) {
    int lrow = l0 + wave * 32 + mt * 16 + q * 4;
    #pragma unroll
    for (int nt = 0; nt < 4; ++nt) {
      int c = nt * 16 + m;
      float bias = c2b[c];
      #pragma unroll
      for (int r = 0; r < 4; ++r)
        c2o[(size_t)(b * L_ + lrow + r) * 64 + c] = f2bf(acc[mt][nt][r] + bias);
    }
  }
}

// ---------------------------------------------------------------------------
// K4 v7: GRU scan. R6 proved weights resident (VGPR 132) but dur unchanged:
// the real bottleneck was __syncthreads' s_waitcnt vmcnt(0) draining the
// per-step x prefetch (HBM ~900 cyc) at every barrier. Fix:
//  (a) x_proj transposed [B,192,L]: per-lane chunk = contiguous dwordx4;
//  (b) 16-step chunks, software-pipelined one full chunk ahead;
//  (c) RAW barriers (s_waitcnt lgkmcnt(0); s_barrier) that do NOT drain
//      vmcnt -> chunk loads stay in flight across all 32 barriers.
// Occupancy cap (waves_per_eu(1,1) + 56 KB LDS) kept from R6.
// ---------------------------------------------------------------------------
#define BARRIER() asm volatile("s_waitcnt lgkmcnt(0)\n\ts_barrier" ::: "memory")

__global__ __launch_bounds__(192)
__attribute__((amdgpu_waves_per_eu(1, 1)))
void k_scan(
    const unsigned short* __restrict__ xprojT, const float* __restrict__ Wh,
    const float* __restrict__ bg, float* __restrict__ h_t)
{
  // 14336 floats = 56 KB backstop: h_lds=[0,64), s_z=[64,128), s_r=[128,192)
  __shared__ __align__(16) float lds_pool[14336];
  float* h_lds = lds_pool;
  float* s_z   = lds_pool + 64;
  float* s_r   = lds_pool + 128;

  int b = blockIdx.x;
  int tid = threadIdx.x;
  int wave = tid >> 6, j = tid & 63;
  int o = wave * 64 + j;                  // output column 0..191

#define DECL_W(i) float4 w##i = {Wh[(4*i+0)*192+o], Wh[(4*i+1)*192+o], \
                                 Wh[(4*i+2)*192+o], Wh[(4*i+3)*192+o]};
  DECL_W(0)  DECL_W(1)  DECL_W(2)  DECL_W(3)
  DECL_W(4)  DECL_W(5)  DECL_W(6)  DECL_W(7)
  DECL_W(8)  DECL_W(9)  DECL_W(10) DECL_W(11)
  DECL_W(12) DECL_W(13) DECL_W(14) DECL_W(15)
#undef DECL_W
#define OPAQ(i) asm volatile("" : "+v"(w##i.x), "+v"(w##i.y), "+v"(w##i.z), "+v"(w##i.w));
  OPAQ(0)  OPAQ(1)  OPAQ(2)  OPAQ(3)
  OPAQ(4)  OPAQ(5)  OPAQ(6)  OPAQ(7)
  OPAQ(8)  OPAQ(9)  OPAQ(10) OPAQ(11)
  OPAQ(12) OPAQ(13) OPAQ(14) OPAQ(15)
#undef OPAQ
  float bias = bg[192 + o];               // b_gru[1][o]

  if (wave == 2) h_lds[j] = 0.f;
  float h_old = 0.f;                      // wave2's private copy of h[j]

  const unsigned short* xc = xprojT + ((size_t)b * 192 + o) * L_;
  const float4* hl4 = (const float4*)h_lds;

  // chunk 0 (steps 0..15): 2 dwordx4
  uint4 cur0 = ((const uint4*)xc)[0];
  uint4 cur1 = ((const uint4*)xc)[1];

#define STEP(XU) { \
    BARRIER();  /* A: h_lds ready, s_* free */ \
    float a0 = bias, a1 = 0.f, a2 = 0.f, a3 = 0.f; \
    { float4 h4; \
      h4 = hl4[0];  a0 = fmaf(h4.x, w0.x, a0);  a1 = fmaf(h4.y, w0.y, a1);  a2 = fmaf(h4.z, w0.z, a2);  a3 = fmaf(h4.w, w0.w, a3); \
      h4 = hl4[1];  a0 = fmaf(h4.x, w1.x, a0);  a1 = fmaf(h4.y, w1.y, a1);  a2 = fmaf(h4.z, w1.z, a2);  a3 = fmaf(h4.w, w1.w, a3); \
      h4 = hl4[2];  a0 = fmaf(h4.x, w2.x, a0);  a1 = fmaf(h4.y, w2.y, a1);  a2 = fmaf(h4.z, w2.z, a2);  a3 = fmaf(h4.w, w2.w, a3); \
      h4 = hl4[3];  a0 = fmaf(h4.x, w3.x, a0);  a1 = fmaf(h4.y, w3.y, a1);  a2 = fmaf(h4.z, w3.z, a2);  a3 = fmaf(h4.w, w3.w, a3); \
      h4 = hl4[4];  a0 = fmaf(h4.x, w4.x, a0);  a1 = fmaf(h4.y, w4.y, a1);  a2 = fmaf(h4.z, w4.z, a2);  a3 = fmaf(h4.w, w4.w, a3); \
      h4 = hl4[5];  a0 = fmaf(h4.x, w5.x, a0);  a1 = fmaf(h4.y, w5.y, a1);  a2 = fmaf(h4.z, w5.z, a2);  a3 = fmaf(h4.w, w5.w, a3); \
      h4 = hl4[6];  a0 = fmaf(h4.x, w6.x, a0);  a1 = fmaf(h4.y, w6.y, a1);  a2 = fmaf(h4.z, w6.z, a2);  a3 = fmaf(h4.w, w6.w, a3); \
      h4 = hl4[7];  a0 = fmaf(h4.x, w7.x, a0);  a1 = fmaf(h4.y, w7.y, a1);  a2 = fmaf(h4.z, w7.z, a2);  a3 = fmaf(h4.w, w7.w, a3); \
      h4 = hl4[8];  a0 = fmaf(h4.x, w8.x, a0);  a1 = fmaf(h4.y, w8.y, a1);  a2 = fmaf(h4.z, w8.z, a2);  a3 = fmaf(h4.w, w8.w, a3); \
      h4 = hl4[9];  a0 = fmaf(h4.x, w9.x, a0);  a1 = fmaf(h4.y, w9.y, a1);  a2 = fmaf(h4.z, w9.z, a2);  a3 = fmaf(h4.w, w9.w, a3); \
      h4 = hl4[10]; a0 = fmaf(h4.x, w10.x, a0); a1 = fmaf(h4.y, w10.y, a1); a2 = fmaf(h4.z, w10.z, a2); a3 = fmaf(h4.w, w10.w, a3); \
      h4 = hl4[11]; a0 = fmaf(h4.x, w11.x, a0); a1 = fmaf(h4.y, w11.y, a1); a2 = fmaf(h4.z, w11.z, a2); a3 = fmaf(h4.w, w11.w, a3); \
      h4 = hl4[12]; a0 = fmaf(h4.x, w12.x, a0); a1 = fmaf(h4.y, w12.y, a1); a2 = fmaf(h4.z, w12.z, a2); a3 = fmaf(h4.w, w12.w, a3); \
      h4 = hl4[13]; a0 = fmaf(h4.x, w13.x, a0); a1 = fmaf(h4.y, w13.y, a1); a2 = fmaf(h4.z, w13.z, a2); a3 = fmaf(h4.w, w13.w, a3); \
      h4 = hl4[14]; a0 = fmaf(h4.x, w14.x, a0); a1 = fmaf(h4.y, w14.y, a1); a2 = fmaf(h4.z, w14.z, a2); a3 = fmaf(h4.w, w14.w, a3); \
      h4 = hl4[15]; a0 = fmaf(h4.x, w15.x, a0); a1 = fmaf(h4.y, w15.y, a1); a2 = fmaf(h4.z, w15.z, a2); a3 = fmaf(h4.w, w15.w, a3); } \
    float s = (a0 + a1) + (a2 + a3); \
    float xv = bf2f((unsigned short)(XU)); \
    if (wave == 0)      s_z[j] = 1.f / (1.f + __expf(-(xv + s))); \
    else if (wave == 1) s_r[j] = 1.f / (1.f + __expf(-(xv + s))); \
    BARRIER();  /* B: gates visible, h_lds free */ \
    if (wave == 2) { \
      float z = s_z[j], r = s_r[j]; \
      float e2 = __expf(-2.f * (xv + r * s)); \
      float hh = fmaf(2.f, __frcp_rn(1.f + e2), -1.f); \
      h_old = z * h_old + (1.f - z) * hh; \
      h_lds[j] = h_old; \
    } }

#define STEP8(C) \
    STEP(C.x & 0xffffu) STEP(C.x >> 16) \
    STEP(C.y & 0xffffu) STEP(C.y >> 16) \
    STEP(C.z & 0xffffu) STEP(C.z >> 16) \
    STEP(C.w & 0xffffu) STEP(C.w >> 16)

  for (int t0 = 0; t0 < L_; t0 += 16) {
    // issue next chunk one full chunk (16 steps ~ 9k cyc) ahead of use
    int tn = (t0 + 16 < L_) ? t0 + 16 : t0;
    const uint4* pn = (const uint4*)(xc + tn);
    uint4 nxt0 = pn[0];
    uint4 nxt1 = pn[1];
    STEP8(cur0)
    STEP8(cur1)
    cur0 = nxt0; cur1 = nxt1;
  }
#undef STEP8
#undef STEP
  if (wave == 2) h_t[b * 64 + j] = h_old;
}

// ---------------------------------------------------------------------------
// K5: per-batch tail: L2=c2o*h_t -> l2norm -> conv3 -> softmax alpha ->
//     n_hat = sum alpha*tok -> logits = tok.n_hat + bias -> softmax -> out
// ---------------------------------------------------------------------------
__global__ __launch_bounds__(256) void k_final(
    const unsigned short* __restrict__ tokpad, const unsigned short* __restrict__ c2o,
    const float* __restrict__ h_t, const float* __restrict__ c3w,
    const float* __restrict__ c3b, const float* __restrict__ biasg,
    float* __restrict__ out)
{
  __shared__ float Lf[71 * 65];
  __shared__ float a_lds[2048];
  __shared__ float l_lds[2048];
  __shared__ float red[256];
  __shared__ float nred[512];
  __shared__ float nhat[128];
  __shared__ float ht[64];
  __shared__ float c3[512];
  int b = blockIdx.x, tid = threadIdx.x, lane = tid & 63, wave = tid >> 6;
  if (tid < 64) ht[tid] = h_t[b * 64 + tid];
  for (int i = tid; i < 512; i += 256) c3[i] = c3w[i];
  float c3bias = c3b[0];
  __syncthreads();
  // ---- pass 1: a_logits via normalized features + conv3 (tiles of 64 l) ----
  for (int tile = 0; tile < 32; ++tile) {
    int lt = tile << 6;
    for (int i0 = wave; i0 < 71; i0 += 4) {
      int l = lt - 3 + i0;
      float v = 0.f;
      if (l >= 0 && l < L_) v = bf2f(c2o[((size_t)b * L_ + l) * 64 + lane]) * ht[lane];
      float ss = v * v;
      #pragma unroll
      for (int msk = 1; msk < 64; msk <<= 1) ss += __shfl_xor(ss, msk);
      Lf[i0 * 65 + lane] = v * rsqrtf(ss + 1e-12f);
    }
    __syncthreads();
    {
      int u = lane, part = wave;
      float p = 0.f;
      #pragma unroll
      for (int w = 0; w < 8; ++w)
        #pragma unroll
        for (int cc = 0; cc < 16; ++cc) {
          int c = part * 16 + cc;
          p += Lf[(u + w) * 65 + c] * c3[w * 64 + c];
        }
      red[tid] = p;
    }
    __syncthreads();
    if (tid < 64) a_lds[lt + tid] = red[tid] + red[64 + tid] + red[128 + tid] + red[192 + tid] + c3bias;
    __syncthreads();
  }
  // ---- pass 2: softmax alpha over 2048 ----
  {
    float mx = -1e30f;
    for (int i = tid; i < 2048; i += 256) mx = fmaxf(mx, a_lds[i]);
    #pragma unroll
    for (int msk = 1; msk < 64; msk <<= 1) mx = fmaxf(mx, __shfl_xor(mx, msk));
    if (lane == 0) red[wave] = mx;
    __syncthreads();
    mx = fmaxf(fmaxf(red[0], red[1]), fmaxf(red[2], red[3]));
    float sm = 0.f;
    for (int i = tid; i < 2048; i += 256) sm += __expf(a_lds[i] - mx);
    #pragma unroll
    for (int msk = 1; msk < 64; msk <<= 1) sm += __shfl_xor(sm, msk);
    __syncthreads();
    if (lane == 0) red[wave] = sm;
    __syncthreads();
    sm = red[0] + red[1] + red[2] + red[3];
    float inv = 1.f / sm;
    for (int i = tid; i < 2048; i += 256) a_lds[i] = __expf(a_lds[i] - mx) * inv;
    __syncthreads();
  }
  // ---- pass 3: n_hat[128] = sum_l alpha_l * tok[l][:] ----
  {
    int d2 = tid & 63, g = tid >> 6;
    float ax = 0.f, ay = 0.f;
    for (int l = g; l < L_; l += 4) {
      unsigned int uu = *(const unsigned int*)&tokpad[((size_t)b * LP + PAD + l) * 128 + d2 * 2];
      float al = a_lds[l];
      ax += al * bf2f((unsigned short)(uu & 0xffffu));
      ay += al * bf2f((unsigned short)(uu >> 16));
    }
    nred[g * 128 + d2 * 2] = ax;
    nred[g * 128 + d2 * 2 + 1] = ay;
    __syncthreads();
    if (tid < 128) nhat[tid] = nred[tid] + nred[128 + tid] + nred[256 + tid] + nred[384 + tid];
    __syncthreads();
  }
  // ---- pass 4: logits = tok . n_hat + bias ----
  for (int li = 0; li < 8; ++li) {
    int l = li * 256 + tid;
    const uint4* rowp = (const uint4*)&tokpad[((size_t)b * LP + PAD + l) * 128];
    float s = 0.f;
    #pragma unroll
    for (int jj = 0; jj < 16; ++jj) {
      uint4 uu = rowp[jj];
      s += bf2f((unsigned short)(uu.x & 0xffffu)) * nhat[jj*8+0]
         + bf2f((unsigned short)(uu.x >> 16))     * nhat[jj*8+1]
         + bf2f((unsigned short)(uu.y & 0xffffu)) * nhat[jj*8+2]
         + bf2f((unsigned short)(uu.y >> 16))     * nhat[jj*8+3]
         + bf2f((unsigned short)(uu.z & 0xffffu)) * nhat[jj*8+4]
         + bf2f((unsigned short)(uu.z >> 16))     * nhat[jj*8+5]
         + bf2f((unsigned short)(uu.w & 0xffffu)) * nhat[jj*8+6]
         + bf2f((unsigned short)(uu.w >> 16))     * nhat[jj*8+7];
    }
    l_lds[l] = s + biasg[b * L_ + l];
  }
  __syncthreads();
  // ---- pass 5: final softmax -> out ----
  {
    float mx = -1e30f;
    for (int i = tid; i < 2048; i += 256) mx = fmaxf(mx, l_lds[i]);
    #pragma unroll
    for (int msk = 1; msk < 64; msk <<= 1) mx = fmaxf(mx, __shfl_xor(mx, msk));
    __syncthreads();
    if (lane == 0) red[wave] = mx;
    __syncthreads();
    mx = fmaxf(fmaxf(red[0], red[1]), fmaxf(red[2], red[3]));
    float sm = 0.f;
    for (int i = tid; i < 2048; i += 256) sm += __expf(l_lds[i] - mx);
    #pragma unroll
    for (int msk = 1; msk < 64; msk <<= 1) sm += __shfl_xor(sm, msk);
    __syncthreads();
    if (lane == 0) red[wave] = sm;
    __syncthreads();
    sm = red[0] + red[1] + red[2] + red[3];
    float inv = 1.f / sm;
    for (int i = tid; i < 2048; i += 256) out[b * L_ + i] = __expf(l_lds[i] - mx) * inv;
  }
}

// ---------------------------------------------------------------------------
extern "C" void kernel_launch(void* const* d_in, const int* in_sizes, int n_in,
                              void* d_out, int out_size, void* d_ws, size_t ws_size,
                              hipStream_t stream) {
  const int*   code = (const int*)d_in[0];
  const float* E    = (const float*)d_in[1];
  const float* bt   = (const float*)d_in[2];
  const float* Wx   = (const float*)d_in[3];
  const float* Wh   = (const float*)d_in[4];
  const float* bg   = (const float*)d_in[5];
  const float* c1w  = (const float*)d_in[6];
  const float* c1b  = (const float*)d_in[7];
  const float* c2w  = (const float*)d_in[8];
  const float* c2b  = (const float*)d_in[9];
  const float* c3w  = (const float*)d_in[10];
  const float* c3b  = (const float*)d_in[11];
  char* ws = (char*)d_ws;
  unsigned short* tokpad = (unsigned short*)(ws);               // 33,685,504 B
  unsigned short* l1pad  = (unsigned short*)(ws + 33685504);    // 16,842,752 B
  unsigned short* xprojT = (unsigned short*)(ws + 50528256);    // 50,331,648 B
  unsigned short* c2o    = (unsigned short*)(ws + 100859904);   // 16,777,216 B
  unsigned short* WxT    = (unsigned short*)(ws + 117637120);   //     49,152 B
  unsigned short* c1wT   = (unsigned short*)(ws + 117686272);   //    131,072 B
  unsigned short* c2wT   = (unsigned short*)(ws + 117817344);   //     65,536 B
  float*          htp    = (float*)(ws + 117882880);            //     16,384 B
  float*          biasg  = (float*)(ws + 117899264);            //    524,288 B
  // total ws use: 118,423,552 B

  k_prep <<<9232, 256, 0, stream>>>(code, E, bt, Wx, c1w, c2w, tokpad, l1pad, WxT, c1wT, c2wT, biasg);
  k_xproj<<<1024, 256, 0, stream>>>(tokpad, WxT, bg, xprojT);
  k_scan <<<64, 192, 0, stream>>>(xprojT, Wh, bg, htp);
  k_conv1<<<1024, 256, 0, stream>>>(tokpad, c1wT, c1b, l1pad);
  k_conv2<<<1024, 256, 0, stream>>>(l1pad, c2wT, c2b, c2o);
  k_final<<<64, 256, 0, stream>>>(tokpad, c2o, htp, c3w, c3b, biasg, (float*)d_out);
}